// Round 2
// baseline (156.027 us; speedup 1.0000x reference)
//
#include <hip/hip_runtime.h>

#define BB 64
#define NN 300   // columns (predictions)
#define TT 30    // rows (targets)
#define BIGF 1e18f
#define KPL 5    // columns per lane (64*5 = 320 >= 300)

// d_out is re-poisoned 0xAA before every timed launch -> zero it ourselves.
__global__ void zero_out_kernel(float* out) {
    int tid = threadIdx.x;
    if (tid < 3) out[tid] = 0.0f;
}

// GIoU with exact reference fp32 op order (no fma contraction).
__device__ __forceinline__ float giou_xyxy(float ax0, float ay0, float ax1, float ay1, float area_a,
                                           float bx0, float by0, float bx1, float by1, float area_b) {
    float ltx = fmaxf(ax0, bx0), lty = fmaxf(ay0, by0);
    float rbx = fminf(ax1, bx1), rby = fminf(ay1, by1);
    float w = fmaxf(__fsub_rn(rbx, ltx), 0.0f);
    float h = fmaxf(__fsub_rn(rby, lty), 0.0f);
    float inter = __fmul_rn(w, h);
    float uni = __fsub_rn(__fadd_rn(area_a, area_b), inter);
    float iou = inter / uni;
    float cx0 = fminf(ax0, bx0), cy0 = fminf(ay0, by0);
    float cx1 = fmaxf(ax1, bx1), cy1 = fmaxf(ay1, by1);
    float cw = fmaxf(__fsub_rn(cx1, cx0), 0.0f);
    float ch = fmaxf(__fsub_rn(cy1, cy0), 0.0f);
    float areac = __fmul_rn(cw, ch);
    return __fsub_rn(iou, __fsub_rn(areac, uni) / areac);
}

__launch_bounds__(256, 1)
__global__ void detcrit_kernel(const float* __restrict__ pred_boxes,   // [B,N,4] xywh
                               const float* __restrict__ pred_classes, // [B,N]
                               const float* __restrict__ targets,      // [B,T,4] xywh
                               float* __restrict__ out) {              // [3]
    const int b = blockIdx.x;
    const int tid = threadIdx.x;

    __shared__ float s_pb[NN][4];   // pred xywh
    __shared__ float s_px[NN][4];   // pred xyxy
    __shared__ float s_pa[NN];      // pred area
    __shared__ float s_pc[NN];      // pred class prob
    __shared__ float s_tb[TT][4];   // tgt xywh
    __shared__ float s_tx[TT][4];   // tgt xyxy
    __shared__ float s_ta[TT];      // tgt area
    __shared__ float s_cost[TT][NN];
    __shared__ float s_u[TT];
    __shared__ int   s_col4row[TT];
    __shared__ float s_spcA[64 * KPL];
    __shared__ int   s_pathA[64 * KPL];
    __shared__ int   s_sorted[TT];
    __shared__ unsigned char s_lab[NN];
    __shared__ float s_rc[4], s_rb[4], s_rg[4];

    // ---------------- Phase 0: stage inputs ----------------
    const float4* pbg = (const float4*)(pred_boxes + (size_t)b * NN * 4);
    const float4* tgg = (const float4*)(targets + (size_t)b * TT * 4);
    const float*  pcg = pred_classes + (size_t)b * NN;

    for (int n = tid; n < NN; n += 256) {
        float4 v = pbg[n];
        s_pb[n][0] = v.x; s_pb[n][1] = v.y; s_pb[n][2] = v.z; s_pb[n][3] = v.w;
        float x2 = __fadd_rn(v.x, v.z), y2 = __fadd_rn(v.y, v.w);
        s_px[n][0] = v.x; s_px[n][1] = v.y; s_px[n][2] = x2; s_px[n][3] = y2;
        s_pa[n] = __fmul_rn(__fsub_rn(x2, v.x), __fsub_rn(y2, v.y));
        s_pc[n] = pcg[n];
        s_lab[n] = 0;
    }
    if (tid < TT) {
        float4 v = tgg[tid];
        s_tb[tid][0] = v.x; s_tb[tid][1] = v.y; s_tb[tid][2] = v.z; s_tb[tid][3] = v.w;
        float x2 = __fadd_rn(v.x, v.z), y2 = __fadd_rn(v.y, v.w);
        s_tx[tid][0] = v.x; s_tx[tid][1] = v.y; s_tx[tid][2] = x2; s_tx[tid][3] = y2;
        s_ta[tid] = __fmul_rn(__fsub_rn(x2, v.x), __fsub_rn(y2, v.y));
        s_u[tid] = 0.0f;
        s_col4row[tid] = -1;
    }
    __syncthreads();

    // ---------------- Phase 1: cost matrix [T][N] (LSA orientation) ----------------
    for (int e = tid; e < TT * NN; e += 256) {
        int t = e / NN;
        int n = e - t * NN;
        float g = giou_xyxy(s_px[n][0], s_px[n][1], s_px[n][2], s_px[n][3], s_pa[n],
                            s_tx[t][0], s_tx[t][1], s_tx[t][2], s_tx[t][3], s_ta[t]);
        float l1 = __fadd_rn(__fadd_rn(__fadd_rn(
                       fabsf(__fsub_rn(s_pb[n][0], s_tb[t][0])),
                       fabsf(__fsub_rn(s_pb[n][1], s_tb[t][1]))),
                       fabsf(__fsub_rn(s_pb[n][2], s_tb[t][2]))),
                       fabsf(__fsub_rn(s_pb[n][3], s_tb[t][3])));
        s_cost[t][n] = __fadd_rn(__fadd_rn(-s_pc[n], -g), l1);
    }
    __syncthreads();

    // ---------------- Phase 2: Hungarian — wave-synchronous on wave 0 ----------------
    if (tid < 64) {
        const int lane = tid;
        volatile float* vu    = s_u;
        volatile int*   vc4r  = s_col4row;
        volatile float* vspc  = s_spcA;
        volatile int*   vpath = s_pathA;

        float vdual[KPL];
        float spc[KPL];
        int   path[KPL];
        int   r4c[KPL];
        int   jcol[KPL];
        #pragma unroll
        for (int k = 0; k < KPL; ++k) {
            jcol[k] = lane + 64 * k;
            vdual[k] = 0.0f;
            r4c[k] = -1;
        }
        const int SCinit = (lane < (NN - 64 * (KPL - 1))) ? 0 : (1 << (KPL - 1));

        for (int row = 0; row < TT; ++row) {
            #pragma unroll
            for (int k = 0; k < KPL; ++k) { spc[k] = BIGF; path[k] = 0; }
            int      SC = SCinit;
            unsigned srm = 0;            // SR bitmask (uniform across lanes)
            float    minVal = 0.0f;
            int      cur_i = row;
            int      sink = -1;

            for (int guard = 0; guard < NN + 2; ++guard) {
                srm |= (1u << cur_i);
                float u_cur = vu[cur_i];
                const float* crow = &s_cost[cur_i][0];
                float bestv = __builtin_inff();
                int   bestj = 0x7fffffff;
                #pragma unroll
                for (int k = 0; k < KPL; ++k) {
                    float m;
                    if (!((SC >> k) & 1)) {
                        float red = __fsub_rn(__fsub_rn(__fadd_rn(minVal, crow[jcol[k]]), u_cur), vdual[k]);
                        if (red < spc[k]) { spc[k] = red; path[k] = cur_i; }
                        m = spc[k];
                    } else {
                        m = BIGF;
                    }
                    if (m < bestv || (m == bestv && jcol[k] < bestj)) { bestv = m; bestj = jcol[k]; }
                }
                // 64-lane lexicographic (val, idx) min == first-index argmin
                #pragma unroll
                for (int off = 1; off < 64; off <<= 1) {
                    float ov = __shfl_xor(bestv, off);
                    int   oj = __shfl_xor(bestj, off);
                    if (ov < bestv || (ov == bestv && oj < bestj)) { bestv = ov; bestj = oj; }
                }
                minVal = bestv;
                int owner = bestj & 63;
                int k2    = bestj >> 6;
                if (lane == owner) SC |= (1 << k2);
                int rsel = r4c[0];
                rsel = (k2 == 1) ? r4c[1] : rsel;
                rsel = (k2 == 2) ? r4c[2] : rsel;
                rsel = (k2 == 3) ? r4c[3] : rsel;
                rsel = (k2 == 4) ? r4c[4] : rsel;
                int r = __shfl(rsel, owner);
                if (r < 0) { sink = bestj; break; }
                cur_i = r;
            }

            // spill spc/path for dual update + augmentation (DS in-order per wave)
            #pragma unroll
            for (int k = 0; k < KPL; ++k) {
                if (jcol[k] < NN) { vspc[jcol[k]] = spc[k]; vpath[jcol[k]] = path[k]; }
            }

            // --- dual update u (lanes 0..TT-1), reference order: before augmentation ---
            if (lane < TT) {
                if (lane == row) {
                    vu[lane] = __fadd_rn(vu[lane], minVal);
                } else if ((srm >> lane) & 1) {
                    int cj = vc4r[lane];
                    cj = (cj < 0) ? 0 : ((cj > NN - 1) ? NN - 1 : cj);   // ref clips
                    vu[lane] = __fadd_rn(vu[lane], __fsub_rn(minVal, vspc[cj]));
                }
            }
            // --- dual update v (registers) ---
            #pragma unroll
            for (int k = 0; k < KPL; ++k) {
                if (((SC >> k) & 1) && jcol[k] < NN)
                    vdual[k] = __fsub_rn(vdual[k], __fsub_rn(minVal, spc[k]));
            }

            // --- augmentation (uniform on all 64 lanes) ---
            int j = sink;
            for (int it = 0; it < TT + 2 && sink >= 0; ++it) {
                int i = vpath[j];
                int owner_a = j & 63;
                int kk = j >> 6;
                if (lane == owner_a) {
                    if      (kk == 0) r4c[0] = i;
                    else if (kk == 1) r4c[1] = i;
                    else if (kk == 2) r4c[2] = i;
                    else if (kk == 3) r4c[3] = i;
                    else              r4c[4] = i;
                }
                int nj = vc4r[i];
                vc4r[i] = j;
                if (i == row) break;
                j = nj;
            }
        }
    }
    __syncthreads();

    // ---------------- Phase 3: sort matched indices (boxes_idx) ----------------
    if (tid == 0) {
        for (int i = 0; i < TT; ++i) s_sorted[i] = s_col4row[i];
        for (int i = 1; i < TT; ++i) {
            int key = s_sorted[i];
            int k = i - 1;
            while (k >= 0 && s_sorted[k] > key) { s_sorted[k + 1] = s_sorted[k]; --k; }
            s_sorted[k + 1] = key;
        }
    }
    __syncthreads();
    if (tid < TT) s_lab[s_sorted[tid]] = 1;
    __syncthreads();

    // ---------------- Phase 4: losses ----------------
    float acc_c = 0.0f, acc_b = 0.0f, acc_g = 0.0f;
    for (int n = tid; n < NN; n += 256) {
        float p = s_pc[n];
        float lp = fmaxf(logf(p), -100.0f);
        float lq = fmaxf(logf(__fsub_rn(1.0f, p)), -100.0f);
        acc_c += s_lab[n] ? -lp : -lq;
    }
    if (tid < TT) {
        int t = tid;
        int idx = s_sorted[t];
        acc_b = fabsf(s_pb[idx][0] - s_tb[t][0]) + fabsf(s_pb[idx][1] - s_tb[t][1])
              + fabsf(s_pb[idx][2] - s_tb[t][2]) + fabsf(s_pb[idx][3] - s_tb[t][3]);
        float g = giou_xyxy(s_px[idx][0], s_px[idx][1], s_px[idx][2], s_px[idx][3], s_pa[idx],
                            s_tx[t][0], s_tx[t][1], s_tx[t][2], s_tx[t][3], s_ta[t]);
        acc_g = 1.0f - g;
    }
    for (int off = 32; off; off >>= 1) {
        acc_c += __shfl_down(acc_c, off);
        acc_b += __shfl_down(acc_b, off);
        acc_g += __shfl_down(acc_g, off);
    }
    int wv = tid >> 6;
    if ((tid & 63) == 0) { s_rc[wv] = acc_c; s_rb[wv] = acc_b; s_rg[wv] = acc_g; }
    __syncthreads();
    if (tid == 0) {
        float c  = s_rc[0] + s_rc[1] + s_rc[2] + s_rc[3];
        float bx = s_rb[0] + s_rb[1] + s_rb[2] + s_rb[3];
        float g  = s_rg[0] + s_rg[1] + s_rg[2] + s_rg[3];
        atomicAdd(&out[0], c  * (1.0f / (float)(BB * NN)));
        atomicAdd(&out[1], bx * (1.0f / (float)(BB * TT)));
        atomicAdd(&out[2], g  * (1.0f / (float)(BB * TT)));
    }
}

extern "C" void kernel_launch(void* const* d_in, const int* in_sizes, int n_in,
                              void* d_out, int out_size, void* d_ws, size_t ws_size,
                              hipStream_t stream) {
    const float* pred_boxes   = (const float*)d_in[0];
    const float* pred_classes = (const float*)d_in[1];
    const float* targets      = (const float*)d_in[2];
    float* out = (float*)d_out;

    zero_out_kernel<<<1, 64, 0, stream>>>(out);
    detcrit_kernel<<<BB, 256, 0, stream>>>(pred_boxes, pred_classes, targets, out);
}

// Round 3
// 112.035 us; speedup vs baseline: 1.3927x; 1.3927x over previous
//
#include <hip/hip_runtime.h>

#define BB 64
#define NN 300   // columns (predictions)
#define TT 30    // rows (targets)
#define BIGF 1e18f
#define KPL 5    // columns per lane (64*5 = 320 >= 300)

// d_out is re-poisoned 0xAA before every timed launch -> zero it ourselves.
__global__ void zero_out_kernel(float* out) {
    int tid = threadIdx.x;
    if (tid < 3) out[tid] = 0.0f;
}

// GIoU with exact reference fp32 op order (no fma contraction).
__device__ __forceinline__ float giou_xyxy(float ax0, float ay0, float ax1, float ay1, float area_a,
                                           float bx0, float by0, float bx1, float by1, float area_b) {
    float ltx = fmaxf(ax0, bx0), lty = fmaxf(ay0, by0);
    float rbx = fminf(ax1, bx1), rby = fminf(ay1, by1);
    float w = fmaxf(__fsub_rn(rbx, ltx), 0.0f);
    float h = fmaxf(__fsub_rn(rby, lty), 0.0f);
    float inter = __fmul_rn(w, h);
    float uni = __fsub_rn(__fadd_rn(area_a, area_b), inter);
    float iou = inter / uni;
    float cx0 = fminf(ax0, bx0), cy0 = fminf(ay0, by0);
    float cx1 = fmaxf(ax1, bx1), cy1 = fmaxf(ay1, by1);
    float cw = fmaxf(__fsub_rn(cx1, cx0), 0.0f);
    float ch = fmaxf(__fsub_rn(cy1, cy0), 0.0f);
    float areac = __fmul_rn(cw, ch);
    return __fsub_rn(iou, __fsub_rn(areac, uni) / areac);
}

// ---- cross-lane helpers (VALU-pipe, not LDS) ----
__device__ __forceinline__ int   rl_i(int v, int l)   { return __builtin_amdgcn_readlane(v, l); }
__device__ __forceinline__ float rl_f(float v, int l) { return __int_as_float(__builtin_amdgcn_readlane(__float_as_int(v), l)); }

// order-isomorphic float<->uint transform (exact, bit-reversible)
__device__ __forceinline__ unsigned f32_order(float f) {
    unsigned u = __float_as_uint(f);
    return u ^ ((unsigned)((int)u >> 31) | 0x80000000u);
}
__device__ __forceinline__ float f32_unorder(unsigned h) {
    unsigned u = (h & 0x80000000u) ? (h ^ 0x80000000u) : ~h;
    return __uint_as_float(u);
}

// 64-lane min-reduce of a (value,index) packed u64 key via DPP; returns
// the global min broadcast to all lanes (uniform/SGPR after readlane).
__device__ __forceinline__ unsigned long long lexmin_key_dpp(unsigned long long key) {
#define STEPK(ctrl)                                                                                     \
    {                                                                                                   \
        unsigned lo = (unsigned)key, hi = (unsigned)(key >> 32);                                        \
        unsigned olo = (unsigned)__builtin_amdgcn_update_dpp((int)lo, (int)lo, ctrl, 0xF, 0xF, false);  \
        unsigned ohi = (unsigned)__builtin_amdgcn_update_dpp((int)hi, (int)hi, ctrl, 0xF, 0xF, false);  \
        unsigned long long ok = ((unsigned long long)ohi << 32) | olo;                                  \
        key = (ok < key) ? ok : key;                                                                    \
    }
    STEPK(0x111)  // row_shr:1
    STEPK(0x112)  // row_shr:2
    STEPK(0x114)  // row_shr:4
    STEPK(0x118)  // row_shr:8
    STEPK(0x142)  // row_bcast:15
    STEPK(0x143)  // row_bcast:31
#undef STEPK
    unsigned lo = (unsigned)rl_i((int)(unsigned)key, 63);
    unsigned hi = (unsigned)rl_i((int)(unsigned)(key >> 32), 63);
    return ((unsigned long long)hi << 32) | lo;
}

// uniform-k 5-way register select / set
__device__ __forceinline__ int sel5(const int a[KPL], int k) {
    int r = a[0];
    r = (k == 1) ? a[1] : r;
    r = (k == 2) ? a[2] : r;
    r = (k == 3) ? a[3] : r;
    r = (k == 4) ? a[4] : r;
    return r;
}
__device__ __forceinline__ float sel5f(const float a[KPL], int k) {
    float r = a[0];
    r = (k == 1) ? a[1] : r;
    r = (k == 2) ? a[2] : r;
    r = (k == 3) ? a[3] : r;
    r = (k == 4) ? a[4] : r;
    return r;
}

__launch_bounds__(256, 1)
__global__ void detcrit_kernel(const float* __restrict__ pred_boxes,   // [B,N,4] xywh
                               const float* __restrict__ pred_classes, // [B,N]
                               const float* __restrict__ targets,      // [B,T,4] xywh
                               float* __restrict__ out) {              // [3]
    const int b = blockIdx.x;
    const int tid = threadIdx.x;

    __shared__ float s_pb[NN][5];   // pred xywh (padded: kills 8-way bank conflict)
    __shared__ float s_px[NN][5];   // pred xyxy (padded)
    __shared__ float s_pa[NN];      // pred area
    __shared__ float s_pc[NN];      // pred class prob
    __shared__ float s_tb[TT][4];   // tgt xywh (broadcast access, no pad needed)
    __shared__ float s_tx[TT][4];   // tgt xyxy
    __shared__ float s_ta[TT];      // tgt area
    __shared__ float s_cost[TT][NN];
    __shared__ int   s_sorted[TT];
    __shared__ unsigned char s_lab[NN];
    __shared__ float s_rc[4], s_rb[4], s_rg[4];

    // ---------------- Phase 0: stage inputs ----------------
    const float4* pbg = (const float4*)(pred_boxes + (size_t)b * NN * 4);
    const float4* tgg = (const float4*)(targets + (size_t)b * TT * 4);
    const float*  pcg = pred_classes + (size_t)b * NN;

    for (int n = tid; n < NN; n += 256) {
        float4 v = pbg[n];
        s_pb[n][0] = v.x; s_pb[n][1] = v.y; s_pb[n][2] = v.z; s_pb[n][3] = v.w;
        float x2 = __fadd_rn(v.x, v.z), y2 = __fadd_rn(v.y, v.w);
        s_px[n][0] = v.x; s_px[n][1] = v.y; s_px[n][2] = x2; s_px[n][3] = y2;
        s_pa[n] = __fmul_rn(__fsub_rn(x2, v.x), __fsub_rn(y2, v.y));
        s_pc[n] = pcg[n];
        s_lab[n] = 0;
    }
    if (tid < TT) {
        float4 v = tgg[tid];
        s_tb[tid][0] = v.x; s_tb[tid][1] = v.y; s_tb[tid][2] = v.z; s_tb[tid][3] = v.w;
        float x2 = __fadd_rn(v.x, v.z), y2 = __fadd_rn(v.y, v.w);
        s_tx[tid][0] = v.x; s_tx[tid][1] = v.y; s_tx[tid][2] = x2; s_tx[tid][3] = y2;
        s_ta[tid] = __fmul_rn(__fsub_rn(x2, v.x), __fsub_rn(y2, v.y));
    }
    __syncthreads();

    // ---------------- Phase 1: cost matrix [T][N] ----------------
    for (int e = tid; e < TT * NN; e += 256) {
        int t = e / NN;
        int n = e - t * NN;
        float g = giou_xyxy(s_px[n][0], s_px[n][1], s_px[n][2], s_px[n][3], s_pa[n],
                            s_tx[t][0], s_tx[t][1], s_tx[t][2], s_tx[t][3], s_ta[t]);
        float l1 = __fadd_rn(__fadd_rn(__fadd_rn(
                       fabsf(__fsub_rn(s_pb[n][0], s_tb[t][0])),
                       fabsf(__fsub_rn(s_pb[n][1], s_tb[t][1]))),
                       fabsf(__fsub_rn(s_pb[n][2], s_tb[t][2]))),
                       fabsf(__fsub_rn(s_pb[n][3], s_tb[t][3])));
        s_cost[t][n] = __fadd_rn(__fadd_rn(-s_pc[n], -g), l1);
    }
    __syncthreads();

    // ---------------- Phase 2: Hungarian — wave 0, register-resident, DPP reduce ----------------
    if (tid < 64) {
        const int lane = tid;
        float u_reg = 0.0f;    // u[lane] for lane < TT
        int   c4r_reg = -1;    // col4row[lane] for lane < TT

        float vdual[KPL];      // column duals v[j], j = lane + 64k
        float spc[KPL];
        int   path[KPL];
        int   r4c[KPL];        // row4col[j]
        #pragma unroll
        for (int k = 0; k < KPL; ++k) { vdual[k] = 0.0f; r4c[k] = -1; }
        // columns j >= NN permanently "visited"
        const int SCinit = (lane < (NN - 64 * (KPL - 1))) ? 0 : (1 << (KPL - 1));

        for (int row = 0; row < TT; ++row) {
            #pragma unroll
            for (int k = 0; k < KPL; ++k) { spc[k] = BIGF; path[k] = 0; }
            int      SC = SCinit;
            unsigned srm = 0;          // SR bitmask (uniform)
            float    minVal = 0.0f;
            int      cur_i = row;
            int      sink = -1;

            for (int guard = 0; guard < NN + 2; ++guard) {
                srm |= (1u << cur_i);
                float u_cur = rl_f(u_reg, cur_i);          // uniform
                const float* crow = &s_cost[cur_i][0];     // cur_i uniform -> scalar base
                float bestv = __builtin_inff();
                int   bestj = 0x7fffffff;
                #pragma unroll
                for (int k = 0; k < KPL; ++k) {
                    int jc = lane + 64 * k;
                    float m;
                    if (!((SC >> k) & 1)) {
                        float red = __fsub_rn(__fsub_rn(__fadd_rn(minVal, crow[jc]), u_cur), vdual[k]);
                        if (red < spc[k]) { spc[k] = red; path[k] = cur_i; }
                        m = spc[k];
                    } else {
                        m = BIGF;
                    }
                    if (m < bestv || (m == bestv && jc < bestj)) { bestv = m; bestj = jc; }
                }
                // global lexicographic (value, first-index) min via DPP on packed key
                unsigned long long key = ((unsigned long long)f32_order(bestv) << 32) | (unsigned)bestj;
                key = lexmin_key_dpp(key);
                minVal = f32_unorder((unsigned)(key >> 32));
                int bj = (int)(unsigned)(key & 0xffffffffu);

                int owner = bj & 63;     // uniform
                int k2    = bj >> 6;     // uniform
                if (lane == owner) SC |= (1 << k2);
                int rsel = sel5(r4c, k2);
                int r = rl_i(rsel, owner);                 // row4col[bj], uniform
                if (r < 0) { sink = bj; break; }
                cur_i = r;
            }

            // --- dual update u (reference order: before augmentation) ---
            {
                int cj = c4r_reg;
                cj = (cj < 0) ? 0 : ((cj > NN - 1) ? NN - 1 : cj);   // ref clips
                int ou = cj & 63, ku = cj >> 6;                      // per-lane
                // gather spc[cj] across lanes (all 64 lanes execute the shuffles)
                float g0 = __shfl(spc[0], ou);
                float g1 = __shfl(spc[1], ou);
                float g2 = __shfl(spc[2], ou);
                float g3 = __shfl(spc[3], ou);
                float g4 = __shfl(spc[4], ou);
                float selspc = (ku == 0) ? g0 : (ku == 1) ? g1 : (ku == 2) ? g2 : (ku == 3) ? g3 : g4;
                if (lane < TT) {
                    if (lane == row) {
                        u_reg = __fadd_rn(u_reg, minVal);
                    } else if ((srm >> lane) & 1u) {
                        u_reg = __fadd_rn(u_reg, __fsub_rn(minVal, selspc));
                    }
                }
            }
            // --- dual update v (register-local) ---
            #pragma unroll
            for (int k = 0; k < KPL; ++k) {
                if (((SC >> k) & 1) && (lane + 64 * k) < NN)
                    vdual[k] = __fsub_rn(vdual[k], __fsub_rn(minVal, spc[k]));
            }

            // --- augmentation (uniform walk, readlane-based) ---
            int j = sink;
            for (int it = 0; it < TT + 2 && sink >= 0; ++it) {
                int oa = j & 63, ka = j >> 6;    // uniform
                int psel = sel5(path, ka);
                int i = rl_i(psel, oa);          // path[j], uniform
                if (lane == oa) {
                    if      (ka == 0) r4c[0] = i;
                    else if (ka == 1) r4c[1] = i;
                    else if (ka == 2) r4c[2] = i;
                    else if (ka == 3) r4c[3] = i;
                    else              r4c[4] = i;
                }
                int nj = rl_i(c4r_reg, i);       // col4row[i], uniform
                if (lane == i) c4r_reg = j;
                if (i == row) break;
                j = nj;
            }
        }

        // ---------------- Phase 3: rank sort (matching is a permutation -> unique ranks) ----------------
        {
            int myv = c4r_reg;
            int rank = 0;
            #pragma unroll
            for (int m = 0; m < TT; ++m) {
                int vm = rl_i(c4r_reg, m);
                rank += (vm < myv) ? 1 : 0;
            }
            if (lane < TT) {
                s_sorted[rank] = myv;
                s_lab[myv] = 1;
            }
        }
    }
    __syncthreads();

    // ---------------- Phase 4: losses ----------------
    float acc_c = 0.0f, acc_b = 0.0f, acc_g = 0.0f;
    for (int n = tid; n < NN; n += 256) {
        float p = s_pc[n];
        float lp = fmaxf(logf(p), -100.0f);
        float lq = fmaxf(logf(__fsub_rn(1.0f, p)), -100.0f);
        acc_c += s_lab[n] ? -lp : -lq;
    }
    if (tid < TT) {
        int t = tid;
        int idx = s_sorted[t];
        acc_b = fabsf(s_pb[idx][0] - s_tb[t][0]) + fabsf(s_pb[idx][1] - s_tb[t][1])
              + fabsf(s_pb[idx][2] - s_tb[t][2]) + fabsf(s_pb[idx][3] - s_tb[t][3]);
        float g = giou_xyxy(s_px[idx][0], s_px[idx][1], s_px[idx][2], s_px[idx][3], s_pa[idx],
                            s_tx[t][0], s_tx[t][1], s_tx[t][2], s_tx[t][3], s_ta[t]);
        acc_g = 1.0f - g;
    }
    for (int off = 32; off; off >>= 1) {
        acc_c += __shfl_down(acc_c, off);
        acc_b += __shfl_down(acc_b, off);
        acc_g += __shfl_down(acc_g, off);
    }
    int wv = tid >> 6;
    if ((tid & 63) == 0) { s_rc[wv] = acc_c; s_rb[wv] = acc_b; s_rg[wv] = acc_g; }
    __syncthreads();
    if (tid == 0) {
        float c  = s_rc[0] + s_rc[1] + s_rc[2] + s_rc[3];
        float bx = s_rb[0] + s_rb[1] + s_rb[2] + s_rb[3];
        float g  = s_rg[0] + s_rg[1] + s_rg[2] + s_rg[3];
        atomicAdd(&out[0], c  * (1.0f / (float)(BB * NN)));
        atomicAdd(&out[1], bx * (1.0f / (float)(BB * TT)));
        atomicAdd(&out[2], g  * (1.0f / (float)(BB * TT)));
    }
}

extern "C" void kernel_launch(void* const* d_in, const int* in_sizes, int n_in,
                              void* d_out, int out_size, void* d_ws, size_t ws_size,
                              hipStream_t stream) {
    const float* pred_boxes   = (const float*)d_in[0];
    const float* pred_classes = (const float*)d_in[1];
    const float* targets      = (const float*)d_in[2];
    float* out = (float*)d_out;

    zero_out_kernel<<<1, 64, 0, stream>>>(out);
    detcrit_kernel<<<BB, 256, 0, stream>>>(pred_boxes, pred_classes, targets, out);
}

// Round 4
// 104.182 us; speedup vs baseline: 1.4976x; 1.0754x over previous
//
#include <hip/hip_runtime.h>

#define BB 64
#define NN 300   // columns (predictions)
#define TT 30    // rows (targets)
#define BIGF 1e18f
#define KPL 5    // columns per lane (64*5 = 320 >= 300)

// GIoU with exact reference fp32 op order (no fma contraction).
__device__ __forceinline__ float giou_xyxy(float ax0, float ay0, float ax1, float ay1, float area_a,
                                           float bx0, float by0, float bx1, float by1, float area_b) {
    float ltx = fmaxf(ax0, bx0), lty = fmaxf(ay0, by0);
    float rbx = fminf(ax1, bx1), rby = fminf(ay1, by1);
    float w = fmaxf(__fsub_rn(rbx, ltx), 0.0f);
    float h = fmaxf(__fsub_rn(rby, lty), 0.0f);
    float inter = __fmul_rn(w, h);
    float uni = __fsub_rn(__fadd_rn(area_a, area_b), inter);
    float iou = inter / uni;
    float cx0 = fminf(ax0, bx0), cy0 = fminf(ay0, by0);
    float cx1 = fmaxf(ax1, bx1), cy1 = fmaxf(ay1, by1);
    float cw = fmaxf(__fsub_rn(cx1, cx0), 0.0f);
    float ch = fmaxf(__fsub_rn(cy1, cy0), 0.0f);
    float areac = __fmul_rn(cw, ch);
    return __fsub_rn(iou, __fsub_rn(areac, uni) / areac);
}

// ---- cross-lane helpers (VALU-pipe, not LDS) ----
__device__ __forceinline__ int   rl_i(int v, int l)   { return __builtin_amdgcn_readlane(v, l); }
__device__ __forceinline__ float rl_f(float v, int l) { return __int_as_float(__builtin_amdgcn_readlane(__float_as_int(v), l)); }

// order-isomorphic float<->uint transform (exact, bit-reversible)
__device__ __forceinline__ unsigned f32_order(float f) {
    unsigned u = __float_as_uint(f);
    return u ^ ((unsigned)((int)u >> 31) | 0x80000000u);
}
__device__ __forceinline__ float f32_unorder(unsigned h) {
    unsigned u = (h & 0x80000000u) ? (h ^ 0x80000000u) : ~h;
    return __uint_as_float(u);
}

// 64-lane min-reduce of a (value,index) packed u64 key via DPP; returns
// the global min broadcast to all lanes (uniform after readlane 63).
__device__ __forceinline__ unsigned long long lexmin_key_dpp(unsigned long long key) {
#define STEPK(ctrl)                                                                                     \
    {                                                                                                   \
        unsigned lo = (unsigned)key, hi = (unsigned)(key >> 32);                                        \
        unsigned olo = (unsigned)__builtin_amdgcn_update_dpp((int)lo, (int)lo, ctrl, 0xF, 0xF, false);  \
        unsigned ohi = (unsigned)__builtin_amdgcn_update_dpp((int)hi, (int)hi, ctrl, 0xF, 0xF, false);  \
        unsigned long long ok = ((unsigned long long)ohi << 32) | olo;                                  \
        key = (ok < key) ? ok : key;                                                                    \
    }
    STEPK(0x111)  // row_shr:1
    STEPK(0x112)  // row_shr:2
    STEPK(0x114)  // row_shr:4
    STEPK(0x118)  // row_shr:8
    STEPK(0x142)  // row_bcast:15
    STEPK(0x143)  // row_bcast:31
#undef STEPK
    unsigned lo = (unsigned)rl_i((int)(unsigned)key, 63);
    unsigned hi = (unsigned)rl_i((int)(unsigned)(key >> 32), 63);
    return ((unsigned long long)hi << 32) | lo;
}

// uniform-k 5-way register select
__device__ __forceinline__ int sel5(const int a[KPL], int k) {
    int r = a[0];
    r = (k == 1) ? a[1] : r;
    r = (k == 2) ? a[2] : r;
    r = (k == 3) ? a[3] : r;
    r = (k == 4) ? a[4] : r;
    return r;
}

__launch_bounds__(256, 1)
__global__ void detcrit_kernel(const float* __restrict__ pred_boxes,   // [B,N,4] xywh
                               const float* __restrict__ pred_classes, // [B,N]
                               const float* __restrict__ targets,      // [B,T,4] xywh
                               float* __restrict__ out) {              // [3]
    const int b = blockIdx.x;
    const int tid = threadIdx.x;

    __shared__ float s_pb[NN][5];   // pred xywh (padded)
    __shared__ float s_px[NN][5];   // pred xyxy (padded)
    __shared__ float s_pa[NN];      // pred area
    __shared__ float s_pc[NN];      // pred class prob
    __shared__ float s_tb[TT][4];   // tgt xywh
    __shared__ float s_tx[TT][4];   // tgt xyxy
    __shared__ float s_ta[TT];      // tgt area
    __shared__ float s_cost[TT][NN];
    __shared__ int   s_sorted[TT];
    __shared__ unsigned char s_lab[NN];
    __shared__ float s_rc[4], s_rb[4], s_rg[4];

    // ---------------- Phase 0: stage inputs ----------------
    const float4* pbg = (const float4*)(pred_boxes + (size_t)b * NN * 4);
    const float4* tgg = (const float4*)(targets + (size_t)b * TT * 4);
    const float*  pcg = pred_classes + (size_t)b * NN;

    for (int n = tid; n < NN; n += 256) {
        float4 v = pbg[n];
        s_pb[n][0] = v.x; s_pb[n][1] = v.y; s_pb[n][2] = v.z; s_pb[n][3] = v.w;
        float x2 = __fadd_rn(v.x, v.z), y2 = __fadd_rn(v.y, v.w);
        s_px[n][0] = v.x; s_px[n][1] = v.y; s_px[n][2] = x2; s_px[n][3] = y2;
        s_pa[n] = __fmul_rn(__fsub_rn(x2, v.x), __fsub_rn(y2, v.y));
        s_pc[n] = pcg[n];
        s_lab[n] = 0;
    }
    if (tid < TT) {
        float4 v = tgg[tid];
        s_tb[tid][0] = v.x; s_tb[tid][1] = v.y; s_tb[tid][2] = v.z; s_tb[tid][3] = v.w;
        float x2 = __fadd_rn(v.x, v.z), y2 = __fadd_rn(v.y, v.w);
        s_tx[tid][0] = v.x; s_tx[tid][1] = v.y; s_tx[tid][2] = x2; s_tx[tid][3] = y2;
        s_ta[tid] = __fmul_rn(__fsub_rn(x2, v.x), __fsub_rn(y2, v.y));
    }
    __syncthreads();

    // ---------------- Phase 1: cost matrix [T][N] ----------------
    for (int e = tid; e < TT * NN; e += 256) {
        int t = e / NN;
        int n = e - t * NN;
        float g = giou_xyxy(s_px[n][0], s_px[n][1], s_px[n][2], s_px[n][3], s_pa[n],
                            s_tx[t][0], s_tx[t][1], s_tx[t][2], s_tx[t][3], s_ta[t]);
        float l1 = __fadd_rn(__fadd_rn(__fadd_rn(
                       fabsf(__fsub_rn(s_pb[n][0], s_tb[t][0])),
                       fabsf(__fsub_rn(s_pb[n][1], s_tb[t][1]))),
                       fabsf(__fsub_rn(s_pb[n][2], s_tb[t][2]))),
                       fabsf(__fsub_rn(s_pb[n][3], s_tb[t][3])));
        s_cost[t][n] = __fadd_rn(__fadd_rn(-s_pc[n], -g), l1);
    }
    __syncthreads();

    // ---------------- Phase 2: LSA — wave 0, JV greedy init + SAP for leftovers ----------------
    // Exactness: greedy init gives feasible duals (red>=0, red=0 on matched, v=0);
    // successive-shortest-path then yields the exact optimal matching, which equals
    // the reference's matching whenever the optimum is unique (generic for random fp32).
    if (tid < 64) {
        const int lane = tid;
        float u_reg = 0.0f;    // u[lane] for lane < TT
        int   c4r_reg = -1;    // col4row[lane] for lane < TT

        float vdual[KPL];      // column duals v[j], j = lane + 64k
        float spc[KPL];
        int   path[KPL];
        int   r4c[KPL];        // row4col[j]
        #pragma unroll
        for (int k = 0; k < KPL; ++k) { vdual[k] = 0.0f; r4c[k] = -1; }
        const int SCinit = (lane < (NN - 64 * (KPL - 1))) ? 0 : (1 << (KPL - 1));

        // --- greedy init: u[t] = row min; assign argmin col if free (pipelined loads) ---
        unsigned assignedm = 0;
        {
            float cA[KPL];
            #pragma unroll
            for (int k = 0; k < KPL; ++k) {
                int jc = lane + 64 * k;
                cA[k] = (jc < NN) ? s_cost[0][jc] : BIGF;
            }
            for (int t = 0; t < TT; ++t) {
                float cB[KPL];
                int tn = (t + 1 < TT) ? t + 1 : TT - 1;
                #pragma unroll
                for (int k = 0; k < KPL; ++k) {
                    int jc = lane + 64 * k;
                    cB[k] = (jc < NN) ? s_cost[tn][jc] : BIGF;
                }
                float bestv = __builtin_inff();
                int   bestj = 0x7fffffff;
                #pragma unroll
                for (int k = 0; k < KPL; ++k) {
                    int jc = lane + 64 * k;
                    if (cA[k] < bestv || (cA[k] == bestv && jc < bestj)) { bestv = cA[k]; bestj = jc; }
                }
                unsigned long long key = ((unsigned long long)f32_order(bestv) << 32) | (unsigned)bestj;
                key = lexmin_key_dpp(key);
                float mv = f32_unorder((unsigned)(key >> 32));
                int   bj = (int)(unsigned)(key & 0xffffffffu);
                if (lane == t) u_reg = mv;
                int owner = bj & 63, k2 = bj >> 6;
                int rcur = rl_i(sel5(r4c, k2), owner);
                if (rcur < 0) {
                    if (lane == owner) {
                        if      (k2 == 0) r4c[0] = t;
                        else if (k2 == 1) r4c[1] = t;
                        else if (k2 == 2) r4c[2] = t;
                        else if (k2 == 3) r4c[3] = t;
                        else              r4c[4] = t;
                    }
                    if (lane == t) c4r_reg = bj;
                    assignedm |= (1u << t);
                }
                #pragma unroll
                for (int k = 0; k < KPL; ++k) cA[k] = cB[k];
            }
        }

        // --- SAP for rows not assigned by greedy ---
        for (int row = 0; row < TT; ++row) {
            if ((assignedm >> row) & 1u) continue;

            #pragma unroll
            for (int k = 0; k < KPL; ++k) { spc[k] = BIGF; path[k] = 0; }
            int      SC = SCinit;
            unsigned srm = 0;
            float    minVal = 0.0f;
            int      cur_i = row;
            int      sink = -1;

            for (int guard = 0; guard < NN + 2; ++guard) {
                srm |= (1u << cur_i);
                float u_cur = rl_f(u_reg, cur_i);
                const float* crow = &s_cost[cur_i][0];
                float bestv = __builtin_inff();
                int   bestj = 0x7fffffff;
                #pragma unroll
                for (int k = 0; k < KPL; ++k) {
                    int jc = lane + 64 * k;
                    float m;
                    if (!((SC >> k) & 1)) {
                        float red = __fsub_rn(__fsub_rn(__fadd_rn(minVal, crow[jc]), u_cur), vdual[k]);
                        if (red < spc[k]) { spc[k] = red; path[k] = cur_i; }
                        m = spc[k];
                    } else {
                        m = BIGF;
                    }
                    if (m < bestv || (m == bestv && jc < bestj)) { bestv = m; bestj = jc; }
                }
                unsigned long long key = ((unsigned long long)f32_order(bestv) << 32) | (unsigned)bestj;
                key = lexmin_key_dpp(key);
                minVal = f32_unorder((unsigned)(key >> 32));
                int bj = (int)(unsigned)(key & 0xffffffffu);

                int owner = bj & 63;
                int k2    = bj >> 6;
                if (lane == owner) SC |= (1 << k2);
                int r = rl_i(sel5(r4c, k2), owner);
                if (r < 0) { sink = bj; break; }
                cur_i = r;
            }

            // --- dual update u (before augmentation) ---
            {
                int cj = c4r_reg;
                cj = (cj < 0) ? 0 : ((cj > NN - 1) ? NN - 1 : cj);
                int ou = cj & 63, ku = cj >> 6;
                float g0 = __shfl(spc[0], ou);
                float g1 = __shfl(spc[1], ou);
                float g2 = __shfl(spc[2], ou);
                float g3 = __shfl(spc[3], ou);
                float g4 = __shfl(spc[4], ou);
                float selspc = (ku == 0) ? g0 : (ku == 1) ? g1 : (ku == 2) ? g2 : (ku == 3) ? g3 : g4;
                if (lane < TT) {
                    if (lane == row) {
                        u_reg = __fadd_rn(u_reg, minVal);
                    } else if ((srm >> lane) & 1u) {
                        u_reg = __fadd_rn(u_reg, __fsub_rn(minVal, selspc));
                    }
                }
            }
            // --- dual update v ---
            #pragma unroll
            for (int k = 0; k < KPL; ++k) {
                if (((SC >> k) & 1) && (lane + 64 * k) < NN)
                    vdual[k] = __fsub_rn(vdual[k], __fsub_rn(minVal, spc[k]));
            }

            // --- augmentation (uniform walk) ---
            int j = sink;
            for (int it = 0; it < TT + 2 && sink >= 0; ++it) {
                int oa = j & 63, ka = j >> 6;
                int i = rl_i(sel5(path, ka), oa);
                if (lane == oa) {
                    if      (ka == 0) r4c[0] = i;
                    else if (ka == 1) r4c[1] = i;
                    else if (ka == 2) r4c[2] = i;
                    else if (ka == 3) r4c[3] = i;
                    else              r4c[4] = i;
                }
                int nj = rl_i(c4r_reg, i);
                if (lane == i) c4r_reg = j;
                if (i == row) break;
                j = nj;
            }
        }

        // ---------------- Phase 3: rank sort (permutation -> unique ranks) ----------------
        {
            int myv = c4r_reg;
            int rank = 0;
            #pragma unroll
            for (int m = 0; m < TT; ++m) {
                int vm = rl_i(c4r_reg, m);
                rank += (vm < myv) ? 1 : 0;
            }
            if (lane < TT) {
                s_sorted[rank] = myv;
                s_lab[myv] = 1;
            }
        }
    }
    __syncthreads();

    // ---------------- Phase 4: losses ----------------
    float acc_c = 0.0f, acc_b = 0.0f, acc_g = 0.0f;
    for (int n = tid; n < NN; n += 256) {
        float p = s_pc[n];
        float lp = fmaxf(logf(p), -100.0f);
        float lq = fmaxf(logf(__fsub_rn(1.0f, p)), -100.0f);
        acc_c += s_lab[n] ? -lp : -lq;
    }
    if (tid < TT) {
        int t = tid;
        int idx = s_sorted[t];
        acc_b = fabsf(s_pb[idx][0] - s_tb[t][0]) + fabsf(s_pb[idx][1] - s_tb[t][1])
              + fabsf(s_pb[idx][2] - s_tb[t][2]) + fabsf(s_pb[idx][3] - s_tb[t][3]);
        float g = giou_xyxy(s_px[idx][0], s_px[idx][1], s_px[idx][2], s_px[idx][3], s_pa[idx],
                            s_tx[t][0], s_tx[t][1], s_tx[t][2], s_tx[t][3], s_ta[t]);
        acc_g = 1.0f - g;
    }
    for (int off = 32; off; off >>= 1) {
        acc_c += __shfl_down(acc_c, off);
        acc_b += __shfl_down(acc_b, off);
        acc_g += __shfl_down(acc_g, off);
    }
    int wv = tid >> 6;
    if ((tid & 63) == 0) { s_rc[wv] = acc_c; s_rb[wv] = acc_b; s_rg[wv] = acc_g; }
    __syncthreads();
    if (tid == 0) {
        float c  = s_rc[0] + s_rc[1] + s_rc[2] + s_rc[3];
        float bx = s_rb[0] + s_rb[1] + s_rb[2] + s_rb[3];
        float g  = s_rg[0] + s_rg[1] + s_rg[2] + s_rg[3];
        atomicAdd(&out[0], c  * (1.0f / (float)(BB * NN)));
        atomicAdd(&out[1], bx * (1.0f / (float)(BB * TT)));
        atomicAdd(&out[2], g  * (1.0f / (float)(BB * TT)));
    }
}

extern "C" void kernel_launch(void* const* d_in, const int* in_sizes, int n_in,
                              void* d_out, int out_size, void* d_ws, size_t ws_size,
                              hipStream_t stream) {
    const float* pred_boxes   = (const float*)d_in[0];
    const float* pred_classes = (const float*)d_in[1];
    const float* targets      = (const float*)d_in[2];
    float* out = (float*)d_out;

    // graph-capture-safe zeroing (harness itself uses hipMemsetAsync on this stream)
    hipMemsetAsync(out, 0, 3 * sizeof(float), stream);
    detcrit_kernel<<<BB, 256, 0, stream>>>(pred_boxes, pred_classes, targets, out);
}

// Round 5
// 88.669 us; speedup vs baseline: 1.7597x; 1.1750x over previous
//
#include <hip/hip_runtime.h>

#define BB 64
#define NN 300   // columns (predictions)
#define TT 30    // rows (targets)
#define BIGF 1e18f
#define KPL 5    // columns per lane (64*5 = 320 >= 300)

// GIoU with exact reference fp32 op order (no fma contraction).
__device__ __forceinline__ float giou_xyxy(float ax0, float ay0, float ax1, float ay1, float area_a,
                                           float bx0, float by0, float bx1, float by1, float area_b) {
    float ltx = fmaxf(ax0, bx0), lty = fmaxf(ay0, by0);
    float rbx = fminf(ax1, bx1), rby = fminf(ay1, by1);
    float w = fmaxf(__fsub_rn(rbx, ltx), 0.0f);
    float h = fmaxf(__fsub_rn(rby, lty), 0.0f);
    float inter = __fmul_rn(w, h);
    float uni = __fsub_rn(__fadd_rn(area_a, area_b), inter);
    float iou = inter / uni;
    float cx0 = fminf(ax0, bx0), cy0 = fminf(ay0, by0);
    float cx1 = fmaxf(ax1, bx1), cy1 = fmaxf(ay1, by1);
    float cw = fmaxf(__fsub_rn(cx1, cx0), 0.0f);
    float ch = fmaxf(__fsub_rn(cy1, cy0), 0.0f);
    float areac = __fmul_rn(cw, ch);
    return __fsub_rn(iou, __fsub_rn(areac, uni) / areac);
}

// ---- cross-lane helpers ----
__device__ __forceinline__ int   rl_i(int v, int l)   { return __builtin_amdgcn_readlane(v, l); }
__device__ __forceinline__ float rl_f(float v, int l) { return __int_as_float(__builtin_amdgcn_readlane(__float_as_int(v), l)); }

// 64-lane f32 min reduce via DPP (row_shr 1/2/4/8 + row_bcast 15/31), result
// valid in lane 63; broadcast uniform via readlane. min-safe: old=src keeps
// own value on lanes with no incoming data.
__device__ __forceinline__ float dpp_min_f32(float g) {
#define SM(ctrl)                                                                                          \
    {                                                                                                     \
        float o = __int_as_float(__builtin_amdgcn_update_dpp(__float_as_int(g), __float_as_int(g),        \
                                                             ctrl, 0xF, 0xF, false));                     \
        g = fminf(g, o);                                                                                  \
    }
    SM(0x111) SM(0x112) SM(0x114) SM(0x118) SM(0x142) SM(0x143)
#undef SM
    return rl_f(g, 63);
}

// first column index j (ascending, j = lane + 64k) whose m[k] == gmin.
// IEEE == groups all equal-value lanes (incl. +-0); priority k asc then lane
// asc == ascending j == jnp.argmin first-index tie-break.
__device__ __forceinline__ int first_match_j(const float m[KPL], float gmin) {
    unsigned long long b0 = __ballot(m[0] == gmin);
    unsigned long long b1 = __ballot(m[1] == gmin);
    unsigned long long b2 = __ballot(m[2] == gmin);
    unsigned long long b3 = __ballot(m[3] == gmin);
    unsigned long long b4 = __ballot(m[4] == gmin);
    if (b0) return       __builtin_ctzll(b0);
    if (b1) return  64 + __builtin_ctzll(b1);
    if (b2) return 128 + __builtin_ctzll(b2);
    if (b3) return 192 + __builtin_ctzll(b3);
    return        256 + __builtin_ctzll(b4);
}

// uniform-k 5-way register select
__device__ __forceinline__ int sel5(const int a[KPL], int k) {
    int r = a[0];
    r = (k == 1) ? a[1] : r;
    r = (k == 2) ? a[2] : r;
    r = (k == 3) ? a[3] : r;
    r = (k == 4) ? a[4] : r;
    return r;
}

__launch_bounds__(256, 1)
__global__ void detcrit_kernel(const float* __restrict__ pred_boxes,   // [B,N,4] xywh
                               const float* __restrict__ pred_classes, // [B,N]
                               const float* __restrict__ targets,      // [B,T,4] xywh
                               float* __restrict__ out) {              // [3]
    const int b = blockIdx.x;
    const int tid = threadIdx.x;
    const int lane = tid & 63;
    const int wave = tid >> 6;

    __shared__ float s_pb[NN][5];   // pred xywh (padded) — phase 4 only
    __shared__ float s_px[NN][5];   // pred xyxy (padded) — phase 4 only
    __shared__ float s_pa[NN];      // pred area          — phase 4 only
    __shared__ float s_pc[NN];      // pred class prob    — phase 4
    __shared__ float s_tb[TT][4];   // tgt xywh
    __shared__ float s_tx[TT][4];   // tgt xyxy
    __shared__ float s_ta[TT];      // tgt area
    __shared__ float s_cost[TT][NN];
    __shared__ float s_rmv[TT];     // per-row min value
    __shared__ int   s_rmj[TT];     // per-row argmin col
    __shared__ int   s_sorted[TT];
    __shared__ unsigned char s_lab[NN];
    __shared__ float s_rc[4], s_rb[4], s_rg[4];

    // ---------------- Phase 0: stage inputs ----------------
    const float4* pbg = (const float4*)(pred_boxes + (size_t)b * NN * 4);
    const float4* tgg = (const float4*)(targets + (size_t)b * TT * 4);
    const float*  pcg = pred_classes + (size_t)b * NN;

    // per-wave register copy of pred data (lane owns columns jc = lane + 64k)
    float rbx[KPL], rby[KPL], rbw[KPL], rbh[KPL];  // xywh
    float rx2[KPL], ry2[KPL], rpa[KPL], rpc[KPL];  // x2,y2,area,class
    #pragma unroll
    for (int k = 0; k < KPL; ++k) {
        int jc = lane + 64 * k;
        if (jc < NN) {
            float4 v = pbg[jc];
            rbx[k] = v.x; rby[k] = v.y; rbw[k] = v.z; rbh[k] = v.w;
            rx2[k] = __fadd_rn(v.x, v.z);
            ry2[k] = __fadd_rn(v.y, v.w);
            rpa[k] = __fmul_rn(__fsub_rn(rx2[k], v.x), __fsub_rn(ry2[k], v.y));
            rpc[k] = pcg[jc];
        } else {
            rbx[k] = rby[k] = rbw[k] = rbh[k] = 0.0f;
            rx2[k] = ry2[k] = rpa[k] = rpc[k] = 0.0f;
        }
    }

    // LDS staging for phases 3/4 (and targets for phase 1)
    for (int n = tid; n < NN; n += 256) {
        float4 v = pbg[n];
        s_pb[n][0] = v.x; s_pb[n][1] = v.y; s_pb[n][2] = v.z; s_pb[n][3] = v.w;
        float x2 = __fadd_rn(v.x, v.z), y2 = __fadd_rn(v.y, v.w);
        s_px[n][0] = v.x; s_px[n][1] = v.y; s_px[n][2] = x2; s_px[n][3] = y2;
        s_pa[n] = __fmul_rn(__fsub_rn(x2, v.x), __fsub_rn(y2, v.y));
        s_pc[n] = pcg[n];
        s_lab[n] = 0;
    }
    if (tid < TT) {
        float4 v = tgg[tid];
        s_tb[tid][0] = v.x; s_tb[tid][1] = v.y; s_tb[tid][2] = v.z; s_tb[tid][3] = v.w;
        float x2 = __fadd_rn(v.x, v.z), y2 = __fadd_rn(v.y, v.w);
        s_tx[tid][0] = v.x; s_tx[tid][1] = v.y; s_tx[tid][2] = x2; s_tx[tid][3] = y2;
        s_ta[tid] = __fmul_rn(__fsub_rn(x2, v.x), __fsub_rn(y2, v.y));
    }
    __syncthreads();

    // ---------------- Phase 1: cost matrix + per-row argmin (all 4 waves) ----------------
    for (int t = wave; t < TT; t += 4) {
        float tbx = s_tb[t][0], tby = s_tb[t][1], tbw = s_tb[t][2], tbh = s_tb[t][3];
        float tx2 = __fadd_rn(tbx, tbw), ty2 = __fadd_rn(tby, tbh);
        float tta = __fmul_rn(__fsub_rn(tx2, tbx), __fsub_rn(ty2, tby));

        float m[KPL];
        #pragma unroll
        for (int k = 0; k < KPL; ++k) {
            int jc = lane + 64 * k;
            float cv = BIGF;
            if (jc < NN) {
                float g = giou_xyxy(rbx[k], rby[k], rx2[k], ry2[k], rpa[k],
                                    tbx, tby, tx2, ty2, tta);
                float l1 = __fadd_rn(__fadd_rn(__fadd_rn(
                               fabsf(__fsub_rn(rbx[k], tbx)),
                               fabsf(__fsub_rn(rby[k], tby))),
                               fabsf(__fsub_rn(rbw[k], tbw))),
                               fabsf(__fsub_rn(rbh[k], tbh)));
                cv = __fadd_rn(__fadd_rn(-rpc[k], -g), l1);
                s_cost[t][jc] = cv;
            }
            m[k] = cv;
        }
        float gm = fminf(fminf(fminf(m[0], m[1]), fminf(m[2], m[3])), m[4]);
        gm = dpp_min_f32(gm);
        int bj = first_match_j(m, gm);
        if (lane == 0) { s_rmv[t] = gm; s_rmj[t] = bj; }
    }
    __syncthreads();

    // ---------------- Phase 2: LSA — wave 0: greedy init + SAP for leftovers ----------------
    // Greedy init gives feasible duals (red>=0, red=0 on matched, v=0); SAP from
    // those duals yields the exact optimum == reference matching (unique optimum
    // generic for random fp32 costs; verified absmax 0.0 in R3/R4).
    if (tid < 64) {
        float u_reg = 0.0f;    // u[lane] for lane < TT
        int   c4r_reg = -1;    // col4row[lane] for lane < TT

        float vdual[KPL];
        float spc[KPL];
        int   path[KPL];
        int   r4c[KPL];
        #pragma unroll
        for (int k = 0; k < KPL; ++k) { vdual[k] = 0.0f; r4c[k] = -1; }
        const int SCinit = (lane < (NN - 64 * (KPL - 1))) ? 0 : (1 << (KPL - 1));

        // --- greedy: u[t] = row min; assign argmin col if free ---
        unsigned assignedm = 0;
        {
            float rmv_reg = (lane < TT) ? s_rmv[lane] : 0.0f;
            int   rmj_reg = (lane < TT) ? s_rmj[lane] : 0;
            u_reg = (lane < TT) ? rmv_reg : 0.0f;
            for (int t = 0; t < TT; ++t) {
                int j = rl_i(rmj_reg, t);                 // uniform
                int owner = j & 63, k2 = j >> 6;
                int rcur = rl_i(sel5(r4c, k2), owner);
                if (rcur < 0) {
                    if (lane == owner) {
                        if      (k2 == 0) r4c[0] = t;
                        else if (k2 == 1) r4c[1] = t;
                        else if (k2 == 2) r4c[2] = t;
                        else if (k2 == 3) r4c[3] = t;
                        else              r4c[4] = t;
                    }
                    if (lane == t) c4r_reg = j;
                    assignedm |= (1u << t);
                }
            }
        }

        // --- SAP for rows not assigned by greedy ---
        for (int row = 0; row < TT; ++row) {
            if ((assignedm >> row) & 1u) continue;

            #pragma unroll
            for (int k = 0; k < KPL; ++k) { spc[k] = BIGF; path[k] = 0; }
            int      SC = SCinit;
            unsigned srm = 0;
            float    minVal = 0.0f;
            int      cur_i = row;
            int      sink = -1;

            for (int guard = 0; guard < NN + 2; ++guard) {
                srm |= (1u << cur_i);
                const float* crow = &s_cost[cur_i][0];
                float cld[KPL];
                #pragma unroll
                for (int k = 0; k < KPL; ++k)
                    cld[k] = (!((SC >> k) & 1)) ? crow[lane + 64 * k] : 0.0f;
                float u_cur = rl_f(u_reg, cur_i);

                float m[KPL];
                #pragma unroll
                for (int k = 0; k < KPL; ++k) {
                    if (!((SC >> k) & 1)) {
                        float red = __fsub_rn(__fsub_rn(__fadd_rn(minVal, cld[k]), u_cur), vdual[k]);
                        if (red < spc[k]) { spc[k] = red; path[k] = cur_i; }
                        m[k] = spc[k];
                    } else {
                        m[k] = BIGF;
                    }
                }
                float gm = fminf(fminf(fminf(m[0], m[1]), fminf(m[2], m[3])), m[4]);
                gm = dpp_min_f32(gm);
                minVal = gm;
                int bj = first_match_j(m, gm);

                int owner = bj & 63;
                int k2    = bj >> 6;
                if (lane == owner) SC |= (1 << k2);
                int r = rl_i(sel5(r4c, k2), owner);
                if (r < 0) { sink = bj; break; }
                cur_i = r;
            }

            // --- dual update u (before augmentation) ---
            {
                int cj = c4r_reg;
                cj = (cj < 0) ? 0 : ((cj > NN - 1) ? NN - 1 : cj);
                int ou = cj & 63, ku = cj >> 6;
                float g0 = __shfl(spc[0], ou);
                float g1 = __shfl(spc[1], ou);
                float g2 = __shfl(spc[2], ou);
                float g3 = __shfl(spc[3], ou);
                float g4 = __shfl(spc[4], ou);
                float selspc = (ku == 0) ? g0 : (ku == 1) ? g1 : (ku == 2) ? g2 : (ku == 3) ? g3 : g4;
                if (lane < TT) {
                    if (lane == row) {
                        u_reg = __fadd_rn(u_reg, minVal);
                    } else if ((srm >> lane) & 1u) {
                        u_reg = __fadd_rn(u_reg, __fsub_rn(minVal, selspc));
                    }
                }
            }
            // --- dual update v ---
            #pragma unroll
            for (int k = 0; k < KPL; ++k) {
                if (((SC >> k) & 1) && (lane + 64 * k) < NN)
                    vdual[k] = __fsub_rn(vdual[k], __fsub_rn(minVal, spc[k]));
            }

            // --- augmentation (uniform walk) ---
            int j = sink;
            for (int it = 0; it < TT + 2 && sink >= 0; ++it) {
                int oa = j & 63, ka = j >> 6;
                int i = rl_i(sel5(path, ka), oa);
                if (lane == oa) {
                    if      (ka == 0) r4c[0] = i;
                    else if (ka == 1) r4c[1] = i;
                    else if (ka == 2) r4c[2] = i;
                    else if (ka == 3) r4c[3] = i;
                    else              r4c[4] = i;
                }
                int nj = rl_i(c4r_reg, i);
                if (lane == i) c4r_reg = j;
                if (i == row) break;
                j = nj;
            }
        }

        // ---------------- Phase 3: rank sort (permutation -> unique ranks) ----------------
        {
            int myv = c4r_reg;
            int rank = 0;
            #pragma unroll
            for (int mq = 0; mq < TT; ++mq) {
                int vm = rl_i(c4r_reg, mq);
                rank += (vm < myv) ? 1 : 0;
            }
            if (lane < TT) {
                s_sorted[rank] = myv;
                s_lab[myv] = 1;
            }
        }
    }
    __syncthreads();

    // ---------------- Phase 4: losses ----------------
    float acc_c = 0.0f, acc_b = 0.0f, acc_g = 0.0f;
    for (int n = tid; n < NN; n += 256) {
        float p = s_pc[n];
        float lp = fmaxf(logf(p), -100.0f);
        float lq = fmaxf(logf(__fsub_rn(1.0f, p)), -100.0f);
        acc_c += s_lab[n] ? -lp : -lq;
    }
    if (tid < TT) {
        int t = tid;
        int idx = s_sorted[t];
        acc_b = fabsf(s_pb[idx][0] - s_tb[t][0]) + fabsf(s_pb[idx][1] - s_tb[t][1])
              + fabsf(s_pb[idx][2] - s_tb[t][2]) + fabsf(s_pb[idx][3] - s_tb[t][3]);
        float g = giou_xyxy(s_px[idx][0], s_px[idx][1], s_px[idx][2], s_px[idx][3], s_pa[idx],
                            s_tx[t][0], s_tx[t][1], s_tx[t][2], s_tx[t][3], s_ta[t]);
        acc_g = 1.0f - g;
    }
    for (int off = 32; off; off >>= 1) {
        acc_c += __shfl_down(acc_c, off);
        acc_b += __shfl_down(acc_b, off);
        acc_g += __shfl_down(acc_g, off);
    }
    if ((tid & 63) == 0) { s_rc[wave] = acc_c; s_rb[wave] = acc_b; s_rg[wave] = acc_g; }
    __syncthreads();
    if (tid == 0) {
        float c  = s_rc[0] + s_rc[1] + s_rc[2] + s_rc[3];
        float bx = s_rb[0] + s_rb[1] + s_rb[2] + s_rb[3];
        float g  = s_rg[0] + s_rg[1] + s_rg[2] + s_rg[3];
        atomicAdd(&out[0], c  * (1.0f / (float)(BB * NN)));
        atomicAdd(&out[1], bx * (1.0f / (float)(BB * TT)));
        atomicAdd(&out[2], g  * (1.0f / (float)(BB * TT)));
    }
}

extern "C" void kernel_launch(void* const* d_in, const int* in_sizes, int n_in,
                              void* d_out, int out_size, void* d_ws, size_t ws_size,
                              hipStream_t stream) {
    const float* pred_boxes   = (const float*)d_in[0];
    const float* pred_classes = (const float*)d_in[1];
    const float* targets      = (const float*)d_in[2];
    float* out = (float*)d_out;

    hipMemsetAsync(out, 0, 3 * sizeof(float), stream);
    detcrit_kernel<<<BB, 256, 0, stream>>>(pred_boxes, pred_classes, targets, out);
}

// Round 6
// 88.329 us; speedup vs baseline: 1.7664x; 1.0039x over previous
//
#include <hip/hip_runtime.h>

#define BB 64
#define NN 300   // columns (predictions)
#define TT 30    // rows (targets)
#define BIGF 1e18f
#define KPL 5    // columns per lane (64*5 = 320 >= 300)

// GIoU with exact reference fp32 op order (no fma contraction).
__device__ __forceinline__ float giou_xyxy(float ax0, float ay0, float ax1, float ay1, float area_a,
                                           float bx0, float by0, float bx1, float by1, float area_b) {
    float ltx = fmaxf(ax0, bx0), lty = fmaxf(ay0, by0);
    float rbx = fminf(ax1, bx1), rby = fminf(ay1, by1);
    float w = fmaxf(__fsub_rn(rbx, ltx), 0.0f);
    float h = fmaxf(__fsub_rn(rby, lty), 0.0f);
    float inter = __fmul_rn(w, h);
    float uni = __fsub_rn(__fadd_rn(area_a, area_b), inter);
    float iou = inter / uni;
    float cx0 = fminf(ax0, bx0), cy0 = fminf(ay0, by0);
    float cx1 = fmaxf(ax1, bx1), cy1 = fmaxf(ay1, by1);
    float cw = fmaxf(__fsub_rn(cx1, cx0), 0.0f);
    float ch = fmaxf(__fsub_rn(cy1, cy0), 0.0f);
    float areac = __fmul_rn(cw, ch);
    return __fsub_rn(iou, __fsub_rn(areac, uni) / areac);
}

// ---- cross-lane helpers ----
__device__ __forceinline__ int   rl_i(int v, int l)   { return __builtin_amdgcn_readlane(v, l); }
__device__ __forceinline__ float rl_f(float v, int l) { return __int_as_float(__builtin_amdgcn_readlane(__float_as_int(v), l)); }

// 64-lane f32 min reduce via DPP; result broadcast uniform via readlane 63.
__device__ __forceinline__ float dpp_min_f32(float g) {
#define SM(ctrl)                                                                                          \
    {                                                                                                     \
        float o = __int_as_float(__builtin_amdgcn_update_dpp(__float_as_int(g), __float_as_int(g),        \
                                                             ctrl, 0xF, 0xF, false));                     \
        g = fminf(g, o);                                                                                  \
    }
    SM(0x111) SM(0x112) SM(0x114) SM(0x118) SM(0x142) SM(0x143)
#undef SM
    return rl_f(g, 63);
}

// first column index j (ascending, j = lane + 64k) whose m[k] == gmin.
// IEEE == groups equal values; k asc then lane asc == ascending j == first-index.
__device__ __forceinline__ int first_match_j(const float m[KPL], float gmin) {
    unsigned long long b0 = __ballot(m[0] == gmin);
    unsigned long long b1 = __ballot(m[1] == gmin);
    unsigned long long b2 = __ballot(m[2] == gmin);
    unsigned long long b3 = __ballot(m[3] == gmin);
    unsigned long long b4 = __ballot(m[4] == gmin);
    if (b0) return       __builtin_ctzll(b0);
    if (b1) return  64 + __builtin_ctzll(b1);
    if (b2) return 128 + __builtin_ctzll(b2);
    if (b3) return 192 + __builtin_ctzll(b3);
    return        256 + __builtin_ctzll(b4);
}

// 5-way register select (k may be per-lane)
__device__ __forceinline__ int sel5(const int a[KPL], int k) {
    int r = a[0];
    r = (k == 1) ? a[1] : r;
    r = (k == 2) ? a[2] : r;
    r = (k == 3) ? a[3] : r;
    r = (k == 4) ? a[4] : r;
    return r;
}

// cross-lane gather: value a[k] from lane srcLane (per-lane srcLane/k ok)
__device__ __forceinline__ float gather_attr(const float a[KPL], int srcLane, int k) {
    float t0 = __shfl(a[0], srcLane);
    float t1 = __shfl(a[1], srcLane);
    float t2 = __shfl(a[2], srcLane);
    float t3 = __shfl(a[3], srcLane);
    float t4 = __shfl(a[4], srcLane);
    float r = t0;
    r = (k == 1) ? t1 : r;
    r = (k == 2) ? t2 : r;
    r = (k == 3) ? t3 : r;
    r = (k == 4) ? t4 : r;
    return r;
}

__launch_bounds__(256, 1)
__global__ void detcrit_kernel(const float* __restrict__ pred_boxes,   // [B,N,4] xywh
                               const float* __restrict__ pred_classes, // [B,N]
                               const float* __restrict__ targets,      // [B,T,4] xywh
                               float* __restrict__ ws) {               // [B*4] partials
    const int b = blockIdx.x;
    const int tid = threadIdx.x;
    const int lane = tid & 63;
    const int wave = tid >> 6;

    __shared__ float s_tb[TT][4];   // tgt xywh
    __shared__ float s_tx[TT][4];   // tgt xyxy
    __shared__ float s_ta[TT];      // tgt area
    __shared__ float s_cost[TT][NN];
    __shared__ float s_rmv[TT];     // per-row min value
    __shared__ int   s_rmj[TT];     // per-row argmin col
    __shared__ int   s_sorted[TT];

    // ---------------- Phase 0: registers for preds, LDS for targets ----------------
    const float4* pbg = (const float4*)(pred_boxes + (size_t)b * NN * 4);
    const float4* tgg = (const float4*)(targets + (size_t)b * TT * 4);
    const float*  pcg = pred_classes + (size_t)b * NN;

    float rbx[KPL], rby[KPL], rbw[KPL], rbh[KPL];  // xywh
    float rx2[KPL], ry2[KPL], rpa[KPL], rpc[KPL];  // x2,y2,area,class
    #pragma unroll
    for (int k = 0; k < KPL; ++k) {
        int jc = lane + 64 * k;
        if (jc < NN) {
            float4 v = pbg[jc];
            rbx[k] = v.x; rby[k] = v.y; rbw[k] = v.z; rbh[k] = v.w;
            rx2[k] = __fadd_rn(v.x, v.z);
            ry2[k] = __fadd_rn(v.y, v.w);
            rpa[k] = __fmul_rn(__fsub_rn(rx2[k], v.x), __fsub_rn(ry2[k], v.y));
            rpc[k] = pcg[jc];
        } else {
            rbx[k] = rby[k] = rbw[k] = rbh[k] = 0.0f;
            rx2[k] = ry2[k] = rpa[k] = rpc[k] = 0.0f;
        }
    }
    if (tid < TT) {
        float4 v = tgg[tid];
        s_tb[tid][0] = v.x; s_tb[tid][1] = v.y; s_tb[tid][2] = v.z; s_tb[tid][3] = v.w;
        float x2 = __fadd_rn(v.x, v.z), y2 = __fadd_rn(v.y, v.w);
        s_tx[tid][0] = v.x; s_tx[tid][1] = v.y; s_tx[tid][2] = x2; s_tx[tid][3] = y2;
        s_ta[tid] = __fmul_rn(__fsub_rn(x2, v.x), __fsub_rn(y2, v.y));
    }
    __syncthreads();

    // ---------------- Phase 1: cost matrix + per-row argmin (4 waves) ----------------
    for (int t = wave; t < TT; t += 4) {
        float tbx = s_tb[t][0], tby = s_tb[t][1], tbw = s_tb[t][2], tbh = s_tb[t][3];
        float tx2 = __fadd_rn(tbx, tbw), ty2 = __fadd_rn(tby, tbh);
        float tta = __fmul_rn(__fsub_rn(tx2, tbx), __fsub_rn(ty2, tby));

        float m[KPL];
        #pragma unroll
        for (int k = 0; k < KPL; ++k) {
            int jc = lane + 64 * k;
            float cv = BIGF;
            if (jc < NN) {
                float g = giou_xyxy(rbx[k], rby[k], rx2[k], ry2[k], rpa[k],
                                    tbx, tby, tx2, ty2, tta);
                float l1 = __fadd_rn(__fadd_rn(__fadd_rn(
                               fabsf(__fsub_rn(rbx[k], tbx)),
                               fabsf(__fsub_rn(rby[k], tby))),
                               fabsf(__fsub_rn(rbw[k], tbw))),
                               fabsf(__fsub_rn(rbh[k], tbh)));
                cv = __fadd_rn(__fadd_rn(-rpc[k], -g), l1);
                s_cost[t][jc] = cv;
            }
            m[k] = cv;
        }
        float gm = fminf(fminf(fminf(m[0], m[1]), fminf(m[2], m[3])), m[4]);
        gm = dpp_min_f32(gm);
        int bj = first_match_j(m, gm);
        if (lane == 0) { s_rmv[t] = gm; s_rmj[t] = bj; }
    }
    __syncthreads();
    // waves 1-3 are done; everything below is wave 0 only (no more barriers).
    if (wave != 0) return;

    // ---------------- Phase 2: LSA — greedy init + SAP for leftovers ----------------
    // Greedy init gives feasible duals (red>=0, red=0 on matched, v=0); SAP from
    // those duals yields the exact optimum == reference matching (unique optimum
    // generic for random fp32 costs; absmax 0.0 verified R3-R5).
    float u_reg = 0.0f;    // u[lane] for lane < TT
    int   c4r_reg = -1;    // col4row[lane] for lane < TT

    float vdual[KPL];
    float spc[KPL];
    int   path[KPL];
    int   r4c[KPL];
    #pragma unroll
    for (int k = 0; k < KPL; ++k) { vdual[k] = 0.0f; r4c[k] = -1; }
    const int SCinit = (lane < (NN - 64 * (KPL - 1))) ? 0 : (1 << (KPL - 1));

    unsigned assignedm = 0;
    {
        float rmv_reg = (lane < TT) ? s_rmv[lane] : 0.0f;
        int   rmj_reg = (lane < TT) ? s_rmj[lane] : 0;
        u_reg = (lane < TT) ? rmv_reg : 0.0f;
        for (int t = 0; t < TT; ++t) {
            int j = rl_i(rmj_reg, t);                 // uniform
            int owner = j & 63, k2 = j >> 6;
            int rcur = rl_i(sel5(r4c, k2), owner);
            if (rcur < 0) {
                if (lane == owner) {
                    if      (k2 == 0) r4c[0] = t;
                    else if (k2 == 1) r4c[1] = t;
                    else if (k2 == 2) r4c[2] = t;
                    else if (k2 == 3) r4c[3] = t;
                    else              r4c[4] = t;
                }
                if (lane == t) c4r_reg = j;
                assignedm |= (1u << t);
            }
        }
    }

    for (int row = 0; row < TT; ++row) {
        if ((assignedm >> row) & 1u) continue;

        #pragma unroll
        for (int k = 0; k < KPL; ++k) { spc[k] = BIGF; path[k] = 0; }
        int      SC = SCinit;
        unsigned srm = 0;
        float    minVal = 0.0f;
        int      cur_i = row;
        int      sink = -1;

        for (int guard = 0; guard < NN + 2; ++guard) {
            srm |= (1u << cur_i);
            const float* crow = &s_cost[cur_i][0];
            float cld[KPL];
            #pragma unroll
            for (int k = 0; k < KPL; ++k)
                cld[k] = (!((SC >> k) & 1)) ? crow[lane + 64 * k] : 0.0f;
            float u_cur = rl_f(u_reg, cur_i);

            float m[KPL];
            #pragma unroll
            for (int k = 0; k < KPL; ++k) {
                if (!((SC >> k) & 1)) {
                    float red = __fsub_rn(__fsub_rn(__fadd_rn(minVal, cld[k]), u_cur), vdual[k]);
                    if (red < spc[k]) { spc[k] = red; path[k] = cur_i; }
                    m[k] = spc[k];
                } else {
                    m[k] = BIGF;
                }
            }
            float gm = fminf(fminf(fminf(m[0], m[1]), fminf(m[2], m[3])), m[4]);
            gm = dpp_min_f32(gm);
            minVal = gm;
            int bj = first_match_j(m, gm);

            int owner = bj & 63;
            int k2    = bj >> 6;
            if (lane == owner) SC |= (1 << k2);
            int r = rl_i(sel5(r4c, k2), owner);
            if (r < 0) { sink = bj; break; }
            cur_i = r;
        }

        // --- dual update u (before augmentation) ---
        {
            int cj = c4r_reg;
            cj = (cj < 0) ? 0 : ((cj > NN - 1) ? NN - 1 : cj);
            int ou = cj & 63, ku = cj >> 6;
            float g0 = __shfl(spc[0], ou);
            float g1 = __shfl(spc[1], ou);
            float g2 = __shfl(spc[2], ou);
            float g3 = __shfl(spc[3], ou);
            float g4 = __shfl(spc[4], ou);
            float selspc = (ku == 0) ? g0 : (ku == 1) ? g1 : (ku == 2) ? g2 : (ku == 3) ? g3 : g4;
            if (lane < TT) {
                if (lane == row) {
                    u_reg = __fadd_rn(u_reg, minVal);
                } else if ((srm >> lane) & 1u) {
                    u_reg = __fadd_rn(u_reg, __fsub_rn(minVal, selspc));
                }
            }
        }
        // --- dual update v ---
        #pragma unroll
        for (int k = 0; k < KPL; ++k) {
            if (((SC >> k) & 1) && (lane + 64 * k) < NN)
                vdual[k] = __fsub_rn(vdual[k], __fsub_rn(minVal, spc[k]));
        }

        // --- augmentation (uniform walk) ---
        int j = sink;
        for (int it = 0; it < TT + 2 && sink >= 0; ++it) {
            int oa = j & 63, ka = j >> 6;
            int i = rl_i(sel5(path, ka), oa);
            if (lane == oa) {
                if      (ka == 0) r4c[0] = i;
                else if (ka == 1) r4c[1] = i;
                else if (ka == 2) r4c[2] = i;
                else if (ka == 3) r4c[3] = i;
                else              r4c[4] = i;
            }
            int nj = rl_i(c4r_reg, i);
            if (lane == i) c4r_reg = j;
            if (i == row) break;
            j = nj;
        }
    }

    // ---------------- Phase 3+4: sort, losses (wave 0, registers) ----------------
    // per-lane 5-bit label mask from the 30 matched columns
    unsigned labm = 0;
    for (int t = 0; t < TT; ++t) {
        int j = rl_i(c4r_reg, t);                 // uniform
        if ((j & 63) == lane) labm |= 1u << (j >> 6);
    }
    float acc_c = 0.0f;
    #pragma unroll
    for (int k = 0; k < KPL; ++k) {
        int jc = lane + 64 * k;
        if (jc < NN) {
            float p = rpc[k];
            float lp = fmaxf(logf(p), -100.0f);
            float lq = fmaxf(logf(__fsub_rn(1.0f, p)), -100.0f);
            acc_c += ((labm >> k) & 1u) ? -lp : -lq;
        }
    }

    // rank sort (permutation -> unique ranks); LDS round-trip in-order per wave
    {
        int myv = c4r_reg;
        int rank = 0;
        #pragma unroll
        for (int mq = 0; mq < TT; ++mq) {
            int vm = rl_i(c4r_reg, mq);
            rank += (vm < myv) ? 1 : 0;
        }
        volatile int* vs = s_sorted;
        if (lane < TT) vs[rank] = myv;
    }
    volatile int* vs = s_sorted;
    int srt = vs[(lane < TT) ? lane : 0];

    // gather matched pred attrs cross-lane (all lanes participate)
    int ow = srt & 63, kk = srt >> 6;
    float gx  = gather_attr(rbx, ow, kk);
    float gy  = gather_attr(rby, ow, kk);
    float gw  = gather_attr(rbw, ow, kk);
    float gh  = gather_attr(rbh, ow, kk);
    float gx2 = gather_attr(rx2, ow, kk);
    float gy2 = gather_attr(ry2, ow, kk);
    float ga  = gather_attr(rpa, ow, kk);

    float acc_b = 0.0f, acc_g = 0.0f;
    if (lane < TT) {
        int t = lane;
        acc_b = fabsf(gx - s_tb[t][0]) + fabsf(gy - s_tb[t][1])
              + fabsf(gw - s_tb[t][2]) + fabsf(gh - s_tb[t][3]);
        float g = giou_xyxy(gx, gy, gx2, gy2, ga,
                            s_tx[t][0], s_tx[t][1], s_tx[t][2], s_tx[t][3], s_ta[t]);
        acc_g = 1.0f - g;
    }
    for (int off = 32; off; off >>= 1) {
        acc_c += __shfl_down(acc_c, off);
        acc_b += __shfl_down(acc_b, off);
        acc_g += __shfl_down(acc_g, off);
    }
    if (lane == 0) {
        float* wsf = ws + b * 4;
        wsf[0] = acc_c;
        wsf[1] = acc_b;
        wsf[2] = acc_g;
    }
}

__global__ void finish_kernel(const float* __restrict__ ws, float* __restrict__ out) {
    int lane = threadIdx.x;   // 64
    float c = ws[lane * 4 + 0];
    float bx = ws[lane * 4 + 1];
    float g = ws[lane * 4 + 2];
    for (int off = 32; off; off >>= 1) {
        c  += __shfl_down(c, off);
        bx += __shfl_down(bx, off);
        g  += __shfl_down(g, off);
    }
    if (lane == 0) {
        out[0] = c  * (1.0f / (float)(BB * NN));
        out[1] = bx * (1.0f / (float)(BB * TT));
        out[2] = g  * (1.0f / (float)(BB * TT));
    }
}

extern "C" void kernel_launch(void* const* d_in, const int* in_sizes, int n_in,
                              void* d_out, int out_size, void* d_ws, size_t ws_size,
                              hipStream_t stream) {
    const float* pred_boxes   = (const float*)d_in[0];
    const float* pred_classes = (const float*)d_in[1];
    const float* targets      = (const float*)d_in[2];
    float* out = (float*)d_out;
    float* ws  = (float*)d_ws;

    detcrit_kernel<<<BB, 256, 0, stream>>>(pred_boxes, pred_classes, targets, ws);
    finish_kernel<<<1, 64, 0, stream>>>(ws, out);
}

// Round 7
// 80.103 us; speedup vs baseline: 1.9478x; 1.1027x over previous
//
#include <hip/hip_runtime.h>

#define BB 64
#define NN 300   // columns (predictions)
#define TT 30    // rows (targets)
#define BIGF 1e18f
#define KPL 5    // columns per lane (64*5 = 320 >= 300)
#define FLAG_MAGIC 0x5EED1234

// GIoU with exact reference fp32 op order (no fma contraction).
__device__ __forceinline__ float giou_xyxy(float ax0, float ay0, float ax1, float ay1, float area_a,
                                           float bx0, float by0, float bx1, float by1, float area_b) {
    float ltx = fmaxf(ax0, bx0), lty = fmaxf(ay0, by0);
    float rbx = fminf(ax1, bx1), rby = fminf(ay1, by1);
    float w = fmaxf(__fsub_rn(rbx, ltx), 0.0f);
    float h = fmaxf(__fsub_rn(rby, lty), 0.0f);
    float inter = __fmul_rn(w, h);
    float uni = __fsub_rn(__fadd_rn(area_a, area_b), inter);
    float iou = inter / uni;
    float cx0 = fminf(ax0, bx0), cy0 = fminf(ay0, by0);
    float cx1 = fmaxf(ax1, bx1), cy1 = fmaxf(ay1, by1);
    float cw = fmaxf(__fsub_rn(cx1, cx0), 0.0f);
    float ch = fmaxf(__fsub_rn(cy1, cy0), 0.0f);
    float areac = __fmul_rn(cw, ch);
    return __fsub_rn(iou, __fsub_rn(areac, uni) / areac);
}

// ---- cross-lane helpers ----
__device__ __forceinline__ int   rl_i(int v, int l)   { return __builtin_amdgcn_readlane(v, l); }
__device__ __forceinline__ float rl_f(float v, int l) { return __int_as_float(__builtin_amdgcn_readlane(__float_as_int(v), l)); }

// 64-lane f32 min reduce via DPP; result broadcast uniform via readlane 63.
__device__ __forceinline__ float dpp_min_f32(float g) {
#define SM(ctrl)                                                                                          \
    {                                                                                                     \
        float o = __int_as_float(__builtin_amdgcn_update_dpp(__float_as_int(g), __float_as_int(g),        \
                                                             ctrl, 0xF, 0xF, false));                     \
        g = fminf(g, o);                                                                                  \
    }
    SM(0x111) SM(0x112) SM(0x114) SM(0x118) SM(0x142) SM(0x143)
#undef SM
    return rl_f(g, 63);
}

// first column index j (ascending, j = lane + 64k) whose m[k] == gmin.
__device__ __forceinline__ int first_match_j(const float m[KPL], float gmin) {
    unsigned long long b0 = __ballot(m[0] == gmin);
    unsigned long long b1 = __ballot(m[1] == gmin);
    unsigned long long b2 = __ballot(m[2] == gmin);
    unsigned long long b3 = __ballot(m[3] == gmin);
    unsigned long long b4 = __ballot(m[4] == gmin);
    if (b0) return       __builtin_ctzll(b0);
    if (b1) return  64 + __builtin_ctzll(b1);
    if (b2) return 128 + __builtin_ctzll(b2);
    if (b3) return 192 + __builtin_ctzll(b3);
    return        256 + __builtin_ctzll(b4);
}

// 5-way register select (k may be per-lane)
__device__ __forceinline__ int sel5(const int a[KPL], int k) {
    int r = a[0];
    r = (k == 1) ? a[1] : r;
    r = (k == 2) ? a[2] : r;
    r = (k == 3) ? a[3] : r;
    r = (k == 4) ? a[4] : r;
    return r;
}

// cross-lane gather: value a[k] from lane srcLane (per-lane srcLane/k ok)
__device__ __forceinline__ float gather_attr(const float a[KPL], int srcLane, int k) {
    float t0 = __shfl(a[0], srcLane);
    float t1 = __shfl(a[1], srcLane);
    float t2 = __shfl(a[2], srcLane);
    float t3 = __shfl(a[3], srcLane);
    float t4 = __shfl(a[4], srcLane);
    float r = t0;
    r = (k == 1) ? t1 : r;
    r = (k == 2) ? t2 : r;
    r = (k == 3) ? t3 : r;
    r = (k == 4) ? t4 : r;
    return r;
}

// agent-scope (device) atomic helpers — cross-XCD-coherent
__device__ __forceinline__ void  st_rel_i(int* p, int v)   { __hip_atomic_store(p, v, __ATOMIC_RELEASE, __HIP_MEMORY_SCOPE_AGENT); }
__device__ __forceinline__ int   ld_acq_i(const int* p)    { return __hip_atomic_load(p, __ATOMIC_ACQUIRE, __HIP_MEMORY_SCOPE_AGENT); }
__device__ __forceinline__ void  st_rlx_f(float* p, float v){ __hip_atomic_store(p, v, __ATOMIC_RELAXED, __HIP_MEMORY_SCOPE_AGENT); }
__device__ __forceinline__ float ld_rlx_f(const float* p)  { return __hip_atomic_load(p, __ATOMIC_RELAXED, __HIP_MEMORY_SCOPE_AGENT); }

__launch_bounds__(256, 1)
__global__ void detcrit_kernel(const float* __restrict__ pred_boxes,   // [B,N,4] xywh
                               const float* __restrict__ pred_classes, // [B,N]
                               const float* __restrict__ targets,      // [B,T,4] xywh
                               float* __restrict__ ws,                 // scratch: partials+flags
                               float* __restrict__ out) {              // [3]
    const int b = blockIdx.x;
    const int tid = threadIdx.x;
    const int lane = tid & 63;
    const int wave = tid >> 6;

    __shared__ float s_tb[TT][4];   // tgt xywh
    __shared__ float s_tx[TT][4];   // tgt xyxy
    __shared__ float s_ta[TT];      // tgt area
    __shared__ float s_cost[TT][NN];
    __shared__ float s_rmv[TT];     // per-row min value
    __shared__ int   s_rmj[TT];     // per-row argmin col
    __shared__ int   s_claim[64 * KPL];

    // ---------------- Phase 0: registers for preds, LDS for targets ----------------
    const float4* pbg = (const float4*)(pred_boxes + (size_t)b * NN * 4);
    const float4* tgg = (const float4*)(targets + (size_t)b * TT * 4);
    const float*  pcg = pred_classes + (size_t)b * NN;

    float rbx[KPL], rby[KPL], rbw[KPL], rbh[KPL];  // xywh
    float rx2[KPL], ry2[KPL], rpa[KPL], rpc[KPL];  // x2,y2,area,class
    #pragma unroll
    for (int k = 0; k < KPL; ++k) {
        int jc = lane + 64 * k;
        if (jc < NN) {
            float4 v = pbg[jc];
            rbx[k] = v.x; rby[k] = v.y; rbw[k] = v.z; rbh[k] = v.w;
            rx2[k] = __fadd_rn(v.x, v.z);
            ry2[k] = __fadd_rn(v.y, v.w);
            rpa[k] = __fmul_rn(__fsub_rn(rx2[k], v.x), __fsub_rn(ry2[k], v.y));
            rpc[k] = pcg[jc];
        } else {
            rbx[k] = rby[k] = rbw[k] = rbh[k] = 0.0f;
            rx2[k] = ry2[k] = rpa[k] = rpc[k] = 0.0f;
        }
    }
    if (tid < TT) {
        float4 v = tgg[tid];
        s_tb[tid][0] = v.x; s_tb[tid][1] = v.y; s_tb[tid][2] = v.z; s_tb[tid][3] = v.w;
        float x2 = __fadd_rn(v.x, v.z), y2 = __fadd_rn(v.y, v.w);
        s_tx[tid][0] = v.x; s_tx[tid][1] = v.y; s_tx[tid][2] = x2; s_tx[tid][3] = y2;
        s_ta[tid] = __fmul_rn(__fsub_rn(x2, v.x), __fsub_rn(y2, v.y));
    }
    __syncthreads();

    // ---------------- Phase 1: cost matrix + per-row argmin (4 waves) ----------------
    for (int t = wave; t < TT; t += 4) {
        float tbx = s_tb[t][0], tby = s_tb[t][1], tbw = s_tb[t][2], tbh = s_tb[t][3];
        float tx2 = __fadd_rn(tbx, tbw), ty2 = __fadd_rn(tby, tbh);
        float tta = __fmul_rn(__fsub_rn(tx2, tbx), __fsub_rn(ty2, tby));

        float m[KPL];
        #pragma unroll
        for (int k = 0; k < KPL; ++k) {
            int jc = lane + 64 * k;
            float cv = BIGF;
            if (jc < NN) {
                float g = giou_xyxy(rbx[k], rby[k], rx2[k], ry2[k], rpa[k],
                                    tbx, tby, tx2, ty2, tta);
                float l1 = __fadd_rn(__fadd_rn(__fadd_rn(
                               fabsf(__fsub_rn(rbx[k], tbx)),
                               fabsf(__fsub_rn(rby[k], tby))),
                               fabsf(__fsub_rn(rbw[k], tbw))),
                               fabsf(__fsub_rn(rbh[k], tbh)));
                cv = __fadd_rn(__fadd_rn(-rpc[k], -g), l1);
                s_cost[t][jc] = cv;
            }
            m[k] = cv;
        }
        float gm = fminf(fminf(fminf(m[0], m[1]), fminf(m[2], m[3])), m[4]);
        gm = dpp_min_f32(gm);
        int bj = first_match_j(m, gm);
        if (lane == 0) { s_rmv[t] = gm; s_rmj[t] = bj; }
    }
    __syncthreads();
    // waves 1-3 are done; everything below is wave 0 only.
    if (wave != 0) return;

    // ---------------- Phase 2: LSA — greedy init + SAP for leftovers ----------------
    // Greedy init gives feasible duals (red>=0, red=0 on matched, v=0); SAP from
    // those duals yields the exact optimum == reference matching (unique optimum
    // generic for random fp32 costs; absmax 0.0 verified R3-R6).
    float u_reg = (lane < TT) ? s_rmv[lane] : 0.0f;   // u[lane]
    int   rmj_reg = (lane < TT) ? s_rmj[lane] : 0;
    int   c4r_reg = -1;                               // col4row[lane]

    float vdual[KPL];
    float spc[KPL];
    int   path[KPL];
    int   r4c[KPL];
    #pragma unroll
    for (int k = 0; k < KPL; ++k) vdual[k] = 0.0f;
    const int SCinit = (lane < (NN - 64 * (KPL - 1))) ? 0 : (1 << (KPL - 1));

    // --- greedy via LDS atomicMin: winner of col = min claimant row ---
    // (identical to sequential greedy: earliest row wins contested columns)
    unsigned assignedm;
    {
        #pragma unroll
        for (int k = 0; k < KPL; ++k) s_claim[lane + 64 * k] = 0x7fffffff;
        if (lane < TT) atomicMin(&s_claim[rmj_reg], lane);
        #pragma unroll
        for (int k = 0; k < KPL; ++k) {
            int cl = s_claim[lane + 64 * k];
            r4c[k] = (cl != 0x7fffffff) ? cl : -1;
        }
        int won = (lane < TT) && (s_claim[rmj_reg] == lane);
        if (won) c4r_reg = rmj_reg;
        assignedm = (unsigned)__ballot(won);   // lanes>=TT contribute 0
    }

    // --- SAP for rows not assigned by greedy ---
    for (int row = 0; row < TT; ++row) {
        if ((assignedm >> row) & 1u) continue;

        #pragma unroll
        for (int k = 0; k < KPL; ++k) { spc[k] = BIGF; path[k] = 0; }
        int      SC = SCinit;
        unsigned srm = 0;
        float    minVal = 0.0f;
        int      cur_i = row;
        int      sink = -1;

        for (int guard = 0; guard < NN + 2; ++guard) {
            srm |= (1u << cur_i);
            const float* crow = &s_cost[cur_i][0];
            float cld[KPL];
            #pragma unroll
            for (int k = 0; k < KPL; ++k)
                cld[k] = (!((SC >> k) & 1)) ? crow[lane + 64 * k] : 0.0f;
            float u_cur = rl_f(u_reg, cur_i);

            float m[KPL];
            #pragma unroll
            for (int k = 0; k < KPL; ++k) {
                if (!((SC >> k) & 1)) {
                    float red = __fsub_rn(__fsub_rn(__fadd_rn(minVal, cld[k]), u_cur), vdual[k]);
                    if (red < spc[k]) { spc[k] = red; path[k] = cur_i; }
                    m[k] = spc[k];
                } else {
                    m[k] = BIGF;
                }
            }
            float gm = fminf(fminf(fminf(m[0], m[1]), fminf(m[2], m[3])), m[4]);
            gm = dpp_min_f32(gm);
            minVal = gm;
            int bj = first_match_j(m, gm);

            int owner = bj & 63;
            int k2    = bj >> 6;
            if (lane == owner) SC |= (1 << k2);
            int r = rl_i(sel5(r4c, k2), owner);
            if (r < 0) { sink = bj; break; }
            cur_i = r;
        }

        // --- dual update u (before augmentation) ---
        {
            int cj = c4r_reg;
            cj = (cj < 0) ? 0 : ((cj > NN - 1) ? NN - 1 : cj);
            int ou = cj & 63, ku = cj >> 6;
            float g0 = __shfl(spc[0], ou);
            float g1 = __shfl(spc[1], ou);
            float g2 = __shfl(spc[2], ou);
            float g3 = __shfl(spc[3], ou);
            float g4 = __shfl(spc[4], ou);
            float selspc = (ku == 0) ? g0 : (ku == 1) ? g1 : (ku == 2) ? g2 : (ku == 3) ? g3 : g4;
            if (lane < TT) {
                if (lane == row) {
                    u_reg = __fadd_rn(u_reg, minVal);
                } else if ((srm >> lane) & 1u) {
                    u_reg = __fadd_rn(u_reg, __fsub_rn(minVal, selspc));
                }
            }
        }
        // --- dual update v ---
        #pragma unroll
        for (int k = 0; k < KPL; ++k) {
            if (((SC >> k) & 1) && (lane + 64 * k) < NN)
                vdual[k] = __fsub_rn(vdual[k], __fsub_rn(minVal, spc[k]));
        }

        // --- augmentation (uniform walk) ---
        int j = sink;
        for (int it = 0; it < TT + 2 && sink >= 0; ++it) {
            int oa = j & 63, ka = j >> 6;
            int i = rl_i(sel5(path, ka), oa);
            if (lane == oa) {
                if      (ka == 0) r4c[0] = i;
                else if (ka == 1) r4c[1] = i;
                else if (ka == 2) r4c[2] = i;
                else if (ka == 3) r4c[3] = i;
                else              r4c[4] = i;
            }
            int nj = rl_i(c4r_reg, i);
            if (lane == i) c4r_reg = j;
            if (i == row) break;
            j = nj;
        }
    }

    // ---------------- Phase 3+4: sort, losses (wave 0, registers) ----------------
    unsigned labm = 0;
    for (int t = 0; t < TT; ++t) {
        int j = rl_i(c4r_reg, t);                 // uniform
        if ((j & 63) == lane) labm |= 1u << (j >> 6);
    }
    float acc_c = 0.0f;
    #pragma unroll
    for (int k = 0; k < KPL; ++k) {
        int jc = lane + 64 * k;
        if (jc < NN) {
            float p = rpc[k];
            float lp = fmaxf(logf(p), -100.0f);
            float lq = fmaxf(logf(__fsub_rn(1.0f, p)), -100.0f);
            acc_c += ((labm >> k) & 1u) ? -lp : -lq;
        }
    }

    // rank sort (permutation -> unique ranks) via ds_permute register push
    int srt;
    {
        int myv = c4r_reg;
        int rank = 0;
        #pragma unroll
        for (int mq = 0; mq < TT; ++mq) {
            int vm = rl_i(c4r_reg, mq);
            rank += (vm < myv) ? 1 : 0;
        }
        int pushed = 0;
        if (lane < TT) pushed = __builtin_amdgcn_ds_permute(rank << 2, myv);
        srt = (lane < TT) ? pushed : 0;
    }

    // gather matched pred attrs cross-lane (all lanes participate)
    int ow = srt & 63, kk = srt >> 6;
    float gx  = gather_attr(rbx, ow, kk);
    float gy  = gather_attr(rby, ow, kk);
    float gw  = gather_attr(rbw, ow, kk);
    float gh  = gather_attr(rbh, ow, kk);
    float gx2 = gather_attr(rx2, ow, kk);
    float gy2 = gather_attr(ry2, ow, kk);
    float ga  = gather_attr(rpa, ow, kk);

    float acc_b = 0.0f, acc_g = 0.0f;
    if (lane < TT) {
        int t = lane;
        acc_b = fabsf(gx - s_tb[t][0]) + fabsf(gy - s_tb[t][1])
              + fabsf(gw - s_tb[t][2]) + fabsf(gh - s_tb[t][3]);
        float g = giou_xyxy(gx, gy, gx2, gy2, ga,
                            s_tx[t][0], s_tx[t][1], s_tx[t][2], s_tx[t][3], s_ta[t]);
        acc_g = 1.0f - g;
    }
    for (int off = 32; off; off >>= 1) {
        acc_c += __shfl_down(acc_c, off);
        acc_b += __shfl_down(acc_b, off);
        acc_g += __shfl_down(acc_g, off);
    }

    // ---------------- Publish partials + last-block finish (fused, no 2nd kernel) ----------------
    // ws layout: partials [b*4 + 0..2] (floats); flags at int offset 256+b.
    int* flags = (int*)ws + 256;
    if (lane == 0) {
        float* wsf = ws + b * 4;
        st_rlx_f(&wsf[0], acc_c);
        st_rlx_f(&wsf[1], acc_b);
        st_rlx_f(&wsf[2], acc_g);
        st_rel_i(&flags[b], FLAG_MAGIC);   // release: orders partials before flag
    }
    // Non-spinning completion check: each lane acquire-loads one flag. The block
    // whose flag-store commits last in coherence order sees all 64 set (>=1 such
    // block guaranteed). Multiple winners write identical bytes to out — benign.
    int fl = ld_acq_i(&flags[lane]);
    unsigned long long all = __ballot(fl == FLAG_MAGIC);
    if (all == 0xFFFFFFFFFFFFFFFFull) {
        float c  = ld_rlx_f(&ws[lane * 4 + 0]);
        float bx = ld_rlx_f(&ws[lane * 4 + 1]);
        float g  = ld_rlx_f(&ws[lane * 4 + 2]);
        for (int off = 32; off; off >>= 1) {
            c  += __shfl_down(c, off);
            bx += __shfl_down(bx, off);
            g  += __shfl_down(g, off);
        }
        if (lane == 0) {
            out[0] = c  * (1.0f / (float)(BB * NN));
            out[1] = bx * (1.0f / (float)(BB * TT));
            out[2] = g  * (1.0f / (float)(BB * TT));
        }
    }
}

extern "C" void kernel_launch(void* const* d_in, const int* in_sizes, int n_in,
                              void* d_out, int out_size, void* d_ws, size_t ws_size,
                              hipStream_t stream) {
    const float* pred_boxes   = (const float*)d_in[0];
    const float* pred_classes = (const float*)d_in[1];
    const float* targets      = (const float*)d_in[2];
    float* out = (float*)d_out;
    float* ws  = (float*)d_ws;

    detcrit_kernel<<<BB, 256, 0, stream>>>(pred_boxes, pred_classes, targets, ws, out);
}

// Round 8
// 78.281 us; speedup vs baseline: 1.9932x; 1.0233x over previous
//
#include <hip/hip_runtime.h>

#define BB 64
#define NN 300   // columns (predictions)
#define TT 30    // rows (targets)
#define BIGF 1e18f
#define KPL 5    // columns per lane (64*5 = 320 >= 300)
#define NWAVE 8  // 512-thread block: 8 waves for phase 1
#define FLAG_MAGIC 0x5EED1234

// GIoU with exact reference fp32 op order (no fma contraction).
__device__ __forceinline__ float giou_xyxy(float ax0, float ay0, float ax1, float ay1, float area_a,
                                           float bx0, float by0, float bx1, float by1, float area_b) {
    float ltx = fmaxf(ax0, bx0), lty = fmaxf(ay0, by0);
    float rbx = fminf(ax1, bx1), rby = fminf(ay1, by1);
    float w = fmaxf(__fsub_rn(rbx, ltx), 0.0f);
    float h = fmaxf(__fsub_rn(rby, lty), 0.0f);
    float inter = __fmul_rn(w, h);
    float uni = __fsub_rn(__fadd_rn(area_a, area_b), inter);
    float iou = inter / uni;
    float cx0 = fminf(ax0, bx0), cy0 = fminf(ay0, by0);
    float cx1 = fmaxf(ax1, bx1), cy1 = fmaxf(ay1, by1);
    float cw = fmaxf(__fsub_rn(cx1, cx0), 0.0f);
    float ch = fmaxf(__fsub_rn(cy1, cy0), 0.0f);
    float areac = __fmul_rn(cw, ch);
    return __fsub_rn(iou, __fsub_rn(areac, uni) / areac);
}

// ---- cross-lane helpers ----
__device__ __forceinline__ int   rl_i(int v, int l)   { return __builtin_amdgcn_readlane(v, l); }
__device__ __forceinline__ float rl_f(float v, int l) { return __int_as_float(__builtin_amdgcn_readlane(__float_as_int(v), l)); }

// 64-lane f32 min reduce via DPP; result broadcast uniform via readlane 63.
__device__ __forceinline__ float dpp_min_f32(float g) {
#define SM(ctrl)                                                                                          \
    {                                                                                                     \
        float o = __int_as_float(__builtin_amdgcn_update_dpp(__float_as_int(g), __float_as_int(g),        \
                                                             ctrl, 0xF, 0xF, false));                     \
        g = fminf(g, o);                                                                                  \
    }
    SM(0x111) SM(0x112) SM(0x114) SM(0x118) SM(0x142) SM(0x143)
#undef SM
    return rl_f(g, 63);
}

// first column index j (ascending, j = lane + 64k) whose m[k] == gmin.
__device__ __forceinline__ int first_match_j(const float m[KPL], float gmin) {
    unsigned long long b0 = __ballot(m[0] == gmin);
    unsigned long long b1 = __ballot(m[1] == gmin);
    unsigned long long b2 = __ballot(m[2] == gmin);
    unsigned long long b3 = __ballot(m[3] == gmin);
    unsigned long long b4 = __ballot(m[4] == gmin);
    if (b0) return       __builtin_ctzll(b0);
    if (b1) return  64 + __builtin_ctzll(b1);
    if (b2) return 128 + __builtin_ctzll(b2);
    if (b3) return 192 + __builtin_ctzll(b3);
    return        256 + __builtin_ctzll(b4);
}

// 5-way register select (k may be per-lane)
__device__ __forceinline__ int sel5(const int a[KPL], int k) {
    int r = a[0];
    r = (k == 1) ? a[1] : r;
    r = (k == 2) ? a[2] : r;
    r = (k == 3) ? a[3] : r;
    r = (k == 4) ? a[4] : r;
    return r;
}

// cross-lane gather: value a[k] from lane srcLane (per-lane srcLane/k ok)
__device__ __forceinline__ float gather_attr(const float a[KPL], int srcLane, int k) {
    float t0 = __shfl(a[0], srcLane);
    float t1 = __shfl(a[1], srcLane);
    float t2 = __shfl(a[2], srcLane);
    float t3 = __shfl(a[3], srcLane);
    float t4 = __shfl(a[4], srcLane);
    float r = t0;
    r = (k == 1) ? t1 : r;
    r = (k == 2) ? t2 : r;
    r = (k == 3) ? t3 : r;
    r = (k == 4) ? t4 : r;
    return r;
}

// agent-scope (device) atomic helpers — cross-XCD-coherent
__device__ __forceinline__ void  st_rel_i(int* p, int v)   { __hip_atomic_store(p, v, __ATOMIC_RELEASE, __HIP_MEMORY_SCOPE_AGENT); }
__device__ __forceinline__ int   ld_acq_i(const int* p)    { return __hip_atomic_load(p, __ATOMIC_ACQUIRE, __HIP_MEMORY_SCOPE_AGENT); }
__device__ __forceinline__ void  st_rlx_f(float* p, float v){ __hip_atomic_store(p, v, __ATOMIC_RELAXED, __HIP_MEMORY_SCOPE_AGENT); }
__device__ __forceinline__ float ld_rlx_f(const float* p)  { return __hip_atomic_load(p, __ATOMIC_RELAXED, __HIP_MEMORY_SCOPE_AGENT); }

__launch_bounds__(64 * NWAVE, 1)
__global__ void detcrit_kernel(const float* __restrict__ pred_boxes,   // [B,N,4] xywh
                               const float* __restrict__ pred_classes, // [B,N]
                               const float* __restrict__ targets,      // [B,T,4] xywh
                               float* __restrict__ ws,                 // scratch: partials+flags
                               float* __restrict__ out) {              // [3]
    const int b = blockIdx.x;
    const int tid = threadIdx.x;
    const int lane = tid & 63;
    const int wave = tid >> 6;

    __shared__ float s_tb[TT][4];   // tgt xywh
    __shared__ float s_tx[TT][4];   // tgt xyxy
    __shared__ float s_ta[TT];      // tgt area
    __shared__ float s_cost[TT][NN];
    __shared__ float s_rmv[TT];     // per-row min value
    __shared__ int   s_rmj[TT];     // per-row argmin col
    __shared__ int   s_claim[64 * KPL];

    // ---------------- Phase 0: registers for preds, LDS for targets ----------------
    const float4* pbg = (const float4*)(pred_boxes + (size_t)b * NN * 4);
    const float4* tgg = (const float4*)(targets + (size_t)b * TT * 4);
    const float*  pcg = pred_classes + (size_t)b * NN;

    float rbx[KPL], rby[KPL], rbw[KPL], rbh[KPL];  // xywh
    float rx2[KPL], ry2[KPL], rpa[KPL], rpc[KPL];  // x2,y2,area,class
    #pragma unroll
    for (int k = 0; k < KPL; ++k) {
        int jc = lane + 64 * k;
        if (jc < NN) {
            float4 v = pbg[jc];
            rbx[k] = v.x; rby[k] = v.y; rbw[k] = v.z; rbh[k] = v.w;
            rx2[k] = __fadd_rn(v.x, v.z);
            ry2[k] = __fadd_rn(v.y, v.w);
            rpa[k] = __fmul_rn(__fsub_rn(rx2[k], v.x), __fsub_rn(ry2[k], v.y));
            rpc[k] = pcg[jc];
        } else {
            rbx[k] = rby[k] = rbw[k] = rbh[k] = 0.0f;
            rx2[k] = ry2[k] = rpa[k] = rpc[k] = 0.0f;
        }
    }
    if (tid < TT) {
        float4 v = tgg[tid];
        s_tb[tid][0] = v.x; s_tb[tid][1] = v.y; s_tb[tid][2] = v.z; s_tb[tid][3] = v.w;
        float x2 = __fadd_rn(v.x, v.z), y2 = __fadd_rn(v.y, v.w);
        s_tx[tid][0] = v.x; s_tx[tid][1] = v.y; s_tx[tid][2] = x2; s_tx[tid][3] = y2;
        s_ta[tid] = __fmul_rn(__fsub_rn(x2, v.x), __fsub_rn(y2, v.y));
    }
    __syncthreads();

    // ---------------- Phase 1: cost matrix + per-row argmin (NWAVE waves) ----------------
    for (int t = wave; t < TT; t += NWAVE) {
        float tbx = s_tb[t][0], tby = s_tb[t][1], tbw = s_tb[t][2], tbh = s_tb[t][3];
        float tx2 = __fadd_rn(tbx, tbw), ty2 = __fadd_rn(tby, tbh);
        float tta = __fmul_rn(__fsub_rn(tx2, tbx), __fsub_rn(ty2, tby));

        float m[KPL];
        #pragma unroll
        for (int k = 0; k < KPL; ++k) {
            int jc = lane + 64 * k;
            float cv = BIGF;
            if (jc < NN) {
                float g = giou_xyxy(rbx[k], rby[k], rx2[k], ry2[k], rpa[k],
                                    tbx, tby, tx2, ty2, tta);
                float l1 = __fadd_rn(__fadd_rn(__fadd_rn(
                               fabsf(__fsub_rn(rbx[k], tbx)),
                               fabsf(__fsub_rn(rby[k], tby))),
                               fabsf(__fsub_rn(rbw[k], tbw))),
                               fabsf(__fsub_rn(rbh[k], tbh)));
                cv = __fadd_rn(__fadd_rn(-rpc[k], -g), l1);
                s_cost[t][jc] = cv;
            }
            m[k] = cv;
        }
        float gm = fminf(fminf(fminf(m[0], m[1]), fminf(m[2], m[3])), m[4]);
        gm = dpp_min_f32(gm);
        int bj = first_match_j(m, gm);
        if (lane == 0) { s_rmv[t] = gm; s_rmj[t] = bj; }
    }
    __syncthreads();
    // waves 1..NWAVE-1 are done; everything below is wave 0 only.
    if (wave != 0) return;

    // ---------------- Phase 2: LSA — greedy init + SAP for leftovers ----------------
    // Greedy init gives feasible duals (red>=0, red=0 on matched, v=0); SAP from
    // those duals yields the exact optimum == reference matching (unique optimum
    // generic for random fp32 costs; absmax <= 0.016 verified R3-R7).
    float u_reg = (lane < TT) ? s_rmv[lane] : 0.0f;   // u[lane]
    int   rmj_reg = (lane < TT) ? s_rmj[lane] : 0;
    int   c4r_reg = -1;                               // col4row[lane]

    float vdual[KPL];
    float spc[KPL];
    int   path[KPL];
    int   r4c[KPL];
    #pragma unroll
    for (int k = 0; k < KPL; ++k) vdual[k] = 0.0f;
    const int SCinit = (lane < (NN - 64 * (KPL - 1))) ? 0 : (1 << (KPL - 1));

    // --- greedy via LDS atomicMin: winner of col = min claimant row ---
    unsigned assignedm;
    {
        #pragma unroll
        for (int k = 0; k < KPL; ++k) s_claim[lane + 64 * k] = 0x7fffffff;
        if (lane < TT) atomicMin(&s_claim[rmj_reg], lane);
        #pragma unroll
        for (int k = 0; k < KPL; ++k) {
            int cl = s_claim[lane + 64 * k];
            r4c[k] = (cl != 0x7fffffff) ? cl : -1;
        }
        int won = (lane < TT) && (s_claim[rmj_reg] == lane);
        if (won) c4r_reg = rmj_reg;
        assignedm = (unsigned)__ballot(won);
    }

    // --- SAP for rows not assigned by greedy ---
    for (int row = 0; row < TT; ++row) {
        if ((assignedm >> row) & 1u) continue;

        #pragma unroll
        for (int k = 0; k < KPL; ++k) { spc[k] = BIGF; path[k] = 0; }
        int      SC = SCinit;
        unsigned srm = 0;
        float    minVal = 0.0f;
        int      cur_i = row;
        int      sink = -1;

        for (int guard = 0; guard < NN + 2; ++guard) {
            srm |= (1u << cur_i);
            const float* crow = &s_cost[cur_i][0];
            float cld[KPL];
            #pragma unroll
            for (int k = 0; k < KPL; ++k)
                cld[k] = (!((SC >> k) & 1)) ? crow[lane + 64 * k] : 0.0f;
            float u_cur = rl_f(u_reg, cur_i);

            float m[KPL];
            #pragma unroll
            for (int k = 0; k < KPL; ++k) {
                if (!((SC >> k) & 1)) {
                    float red = __fsub_rn(__fsub_rn(__fadd_rn(minVal, cld[k]), u_cur), vdual[k]);
                    if (red < spc[k]) { spc[k] = red; path[k] = cur_i; }
                    m[k] = spc[k];
                } else {
                    m[k] = BIGF;
                }
            }
            float gm = fminf(fminf(fminf(m[0], m[1]), fminf(m[2], m[3])), m[4]);
            gm = dpp_min_f32(gm);
            minVal = gm;
            int bj = first_match_j(m, gm);

            int owner = bj & 63;
            int k2    = bj >> 6;
            if (lane == owner) SC |= (1 << k2);
            int r = rl_i(sel5(r4c, k2), owner);
            if (r < 0) { sink = bj; break; }
            cur_i = r;
        }

        // --- dual update u (before augmentation) ---
        {
            int cj = c4r_reg;
            cj = (cj < 0) ? 0 : ((cj > NN - 1) ? NN - 1 : cj);
            int ou = cj & 63, ku = cj >> 6;
            float g0 = __shfl(spc[0], ou);
            float g1 = __shfl(spc[1], ou);
            float g2 = __shfl(spc[2], ou);
            float g3 = __shfl(spc[3], ou);
            float g4 = __shfl(spc[4], ou);
            float selspc = (ku == 0) ? g0 : (ku == 1) ? g1 : (ku == 2) ? g2 : (ku == 3) ? g3 : g4;
            if (lane < TT) {
                if (lane == row) {
                    u_reg = __fadd_rn(u_reg, minVal);
                } else if ((srm >> lane) & 1u) {
                    u_reg = __fadd_rn(u_reg, __fsub_rn(minVal, selspc));
                }
            }
        }
        // --- dual update v ---
        #pragma unroll
        for (int k = 0; k < KPL; ++k) {
            if (((SC >> k) & 1) && (lane + 64 * k) < NN)
                vdual[k] = __fsub_rn(vdual[k], __fsub_rn(minVal, spc[k]));
        }

        // --- augmentation (uniform walk) ---
        int j = sink;
        for (int it = 0; it < TT + 2 && sink >= 0; ++it) {
            int oa = j & 63, ka = j >> 6;
            int i = rl_i(sel5(path, ka), oa);
            if (lane == oa) {
                if      (ka == 0) r4c[0] = i;
                else if (ka == 1) r4c[1] = i;
                else if (ka == 2) r4c[2] = i;
                else if (ka == 3) r4c[3] = i;
                else              r4c[4] = i;
            }
            int nj = rl_i(c4r_reg, i);
            if (lane == i) c4r_reg = j;
            if (i == row) break;
            j = nj;
        }
    }

    // ---------------- Phase 3+4: sort, losses (wave 0, registers) ----------------
    unsigned labm = 0;
    for (int t = 0; t < TT; ++t) {
        int j = rl_i(c4r_reg, t);                 // uniform
        if ((j & 63) == lane) labm |= 1u << (j >> 6);
    }
    float acc_c = 0.0f;
    #pragma unroll
    for (int k = 0; k < KPL; ++k) {
        int jc = lane + 64 * k;
        if (jc < NN) {
            float p = rpc[k];
            float lp = fmaxf(logf(p), -100.0f);
            float lq = fmaxf(logf(__fsub_rn(1.0f, p)), -100.0f);
            acc_c += ((labm >> k) & 1u) ? -lp : -lq;
        }
    }

    // rank sort (permutation -> unique ranks) via ds_permute register push
    int srt;
    {
        int myv = c4r_reg;
        int rank = 0;
        #pragma unroll
        for (int mq = 0; mq < TT; ++mq) {
            int vm = rl_i(c4r_reg, mq);
            rank += (vm < myv) ? 1 : 0;
        }
        int pushed = 0;
        if (lane < TT) pushed = __builtin_amdgcn_ds_permute(rank << 2, myv);
        srt = (lane < TT) ? pushed : 0;
    }

    // gather matched pred attrs cross-lane (all lanes participate)
    int ow = srt & 63, kk = srt >> 6;
    float gx  = gather_attr(rbx, ow, kk);
    float gy  = gather_attr(rby, ow, kk);
    float gw  = gather_attr(rbw, ow, kk);
    float gh  = gather_attr(rbh, ow, kk);
    float gx2 = gather_attr(rx2, ow, kk);
    float gy2 = gather_attr(ry2, ow, kk);
    float ga  = gather_attr(rpa, ow, kk);

    float acc_b = 0.0f, acc_g = 0.0f;
    if (lane < TT) {
        int t = lane;
        acc_b = fabsf(gx - s_tb[t][0]) + fabsf(gy - s_tb[t][1])
              + fabsf(gw - s_tb[t][2]) + fabsf(gh - s_tb[t][3]);
        float g = giou_xyxy(gx, gy, gx2, gy2, ga,
                            s_tx[t][0], s_tx[t][1], s_tx[t][2], s_tx[t][3], s_ta[t]);
        acc_g = 1.0f - g;
    }
    for (int off = 32; off; off >>= 1) {
        acc_c += __shfl_down(acc_c, off);
        acc_b += __shfl_down(acc_b, off);
        acc_g += __shfl_down(acc_g, off);
    }

    // ---------------- Publish partials + last-block finish (fused) ----------------
    // ws layout: partials [b*4 + 0..2] (floats); flags at int offset 256+b.
    int* flags = (int*)ws + 256;
    if (lane == 0) {
        float* wsf = ws + b * 4;
        st_rlx_f(&wsf[0], acc_c);
        st_rlx_f(&wsf[1], acc_b);
        st_rlx_f(&wsf[2], acc_g);
        st_rel_i(&flags[b], FLAG_MAGIC);   // release: orders partials before flag
    }
    // Non-spinning completion check: the block whose flag-store commits last in
    // coherence order sees all 64 set (>=1 such block guaranteed). Multiple
    // winners write identical bytes to out — benign.
    int fl = ld_acq_i(&flags[lane]);
    unsigned long long all = __ballot(fl == FLAG_MAGIC);
    if (all == 0xFFFFFFFFFFFFFFFFull) {
        float c  = ld_rlx_f(&ws[lane * 4 + 0]);
        float bx = ld_rlx_f(&ws[lane * 4 + 1]);
        float g  = ld_rlx_f(&ws[lane * 4 + 2]);
        for (int off = 32; off; off >>= 1) {
            c  += __shfl_down(c, off);
            bx += __shfl_down(bx, off);
            g  += __shfl_down(g, off);
        }
        if (lane == 0) {
            out[0] = c  * (1.0f / (float)(BB * NN));
            out[1] = bx * (1.0f / (float)(BB * TT));
            out[2] = g  * (1.0f / (float)(BB * TT));
        }
    }
}

extern "C" void kernel_launch(void* const* d_in, const int* in_sizes, int n_in,
                              void* d_out, int out_size, void* d_ws, size_t ws_size,
                              hipStream_t stream) {
    const float* pred_boxes   = (const float*)d_in[0];
    const float* pred_classes = (const float*)d_in[1];
    const float* targets      = (const float*)d_in[2];
    float* out = (float*)d_out;
    float* ws  = (float*)d_ws;

    detcrit_kernel<<<BB, 64 * NWAVE, 0, stream>>>(pred_boxes, pred_classes, targets, ws, out);
}